// Round 5
// baseline (292.816 us; speedup 1.0000x reference)
//
#include <hip/hip_runtime.h>
#include <hip/hip_bf16.h>
#include <stdint.h>

#define DM 768
#define DFF 3072
#define NH 12
#define DK 64
#define SS 2048
#define NTOK 4096   // B*S = 2*2048
#define KCH 2       // attention k-chunks: 16x24x2 = 768 blocks = exactly 3/CU

typedef __hip_bfloat16 bf16;
typedef short bf16x8 __attribute__((ext_vector_type(8)));
typedef float f32x4 __attribute__((ext_vector_type(4)));

#define MFMA16(a, b, c) __builtin_amdgcn_mfma_f32_16x16x32_bf16((a), (b), (c), 0, 0, 0)

// 0.125 (1/sqrt(Dk)) * log2(e), folded into the Q projection so attention uses exp2
#define QSCALE 0.18033688011112042f

#if __has_builtin(__builtin_amdgcn_exp2f)
#define EXP2F(x) __builtin_amdgcn_exp2f(x)   // raw v_exp_f32, no libm fixup
#else
#define EXP2F(x) exp2f(x)
#endif

// counted vmcnt waits (T4): per-thread in-order VMEM completion makes
// vmcnt(3) == "my oldest 3 loads (the current tile) have landed".
#define ASM_VMCNT3 asm volatile("s_waitcnt vmcnt(3)" ::: "memory")
#define ASM_VMCNT0 asm volatile("s_waitcnt vmcnt(0)" ::: "memory")

static __device__ __forceinline__ bf16 f2b(float f) { return __float2bfloat16(f); }
static __device__ __forceinline__ unsigned short f2b_bits(float f) {
    bf16 h = __float2bfloat16(f);
    return *reinterpret_cast<unsigned short*>(&h);
}
static __device__ __forceinline__ float b2f(bf16 h) { return __bfloat162float(h); }

// async 16B global->LDS DMA. LDS dest must be wave-uniform base + lane*16.
static __device__ __forceinline__ void g2l16(const void* g, void* l) {
    __builtin_amdgcn_global_load_lds(
        (const __attribute__((address_space(1))) unsigned int*)g,
        (__attribute__((address_space(3))) unsigned int*)(uintptr_t)l,
        16, 0, 0);
}

// ---------------- all 6 weight transposes (fp32->bf16, [K,N]->[N,K]) --------
__global__ __launch_bounds__(256) void transpose_all(const float* Wq, const float* Wk,
                                                     const float* Wv, const float* Wo,
                                                     const float* W1, const float* W2,
                                                     bf16* WqT, bf16* WkT, bf16* WvT,
                                                     bf16* WoT, bf16* W1T, bf16* W2T) {
    __shared__ float tile[32][33];
    int id = blockIdx.x;
    const float* W; bf16* WT; int K, N, n0, k0;
    if (id < 2304) {            // Wq/Wk/Wv/Wo: 768x768, 24x24 blocks each
        int z = id / 576, r = id % 576;
        W  = (z == 0) ? Wq : (z == 1) ? Wk : (z == 2) ? Wv : Wo;
        WT = (z == 0) ? WqT : (z == 1) ? WkT : (z == 2) ? WvT : WoT;
        K = 768; N = 768; n0 = (r % 24) * 32; k0 = (r / 24) * 32;
    } else if (id < 4608) {     // W1: [768,3072] -> [3072,768]
        int r = id - 2304; W = W1; WT = W1T;
        K = 768; N = 3072; n0 = (r % 96) * 32; k0 = (r / 96) * 32;
    } else {                    // W2: [3072,768] -> [768,3072]
        int r = id - 4608; W = W2; WT = W2T;
        K = 3072; N = 768; n0 = (r % 24) * 32; k0 = (r / 24) * 32;
    }
    int tx = threadIdx.x & 31, ty = threadIdx.x >> 5;
#pragma unroll
    for (int r = ty; r < 32; r += 8)
        tile[r][tx] = W[(size_t)(k0 + r) * N + n0 + tx];
    __syncthreads();
#pragma unroll
    for (int r = ty; r < 32; r += 8)
        WT[(size_t)(n0 + r) * K + k0 + tx] = f2b(tile[tx][r]);
}

// ---------------- LayerNorm (unbiased var, eps on std) --------
__global__ __launch_bounds__(256) void ln_fwd(const float* __restrict__ x,
                                              const float* __restrict__ g,
                                              const float* __restrict__ be,
                                              bf16* __restrict__ out) {
    int wid = threadIdx.x >> 6, lane = threadIdx.x & 63;
    int row = blockIdx.x * 4 + wid;
    const float* xr = x + (size_t)row * DM;
    float v[12];
    float s = 0.f;
#pragma unroll
    for (int i = 0; i < 12; ++i) { v[i] = xr[lane + i * 64]; s += v[i]; }
#pragma unroll
    for (int off = 32; off >= 1; off >>= 1) s += __shfl_xor(s, off);
    float mean = s * (1.f / 768.f);
    float s2 = 0.f;
#pragma unroll
    for (int i = 0; i < 12; ++i) { float d = v[i] - mean; s2 += d * d; }
#pragma unroll
    for (int off = 32; off >= 1; off >>= 1) s2 += __shfl_xor(s2, off);
    float rstd = 1.f / (sqrtf(s2 * (1.f / 767.f)) + 1e-6f);
    bf16* orow = out + (size_t)row * DM;
#pragma unroll
    for (int i = 0; i < 12; ++i) {
        int c = lane + i * 64;
        orow[c] = f2b(g[c] * (v[i] - mean) * rstd + be[c]);
    }
}

// ---------------- 128x128 GEMM core, BK=32, dbuf, prefetch-after-barrier -----
// (R7-proven best) 16B chunk c of row r at phys chunk c ^ ((r>>1)&3).
__device__ __forceinline__ void gemm_core(const bf16* __restrict__ A,
                                          const bf16* __restrict__ BT,
                                          int K, int bm, int bn,
                                          bf16* As, bf16* Bs,   // each 2*128*32
                                          f32x4 acc[4][4]) {
    int tid = threadIdx.x;
    int lane = tid & 63, quad = lane >> 4, lid = lane & 15;
    int wid = tid >> 6;
    int wm = (wid >> 1) * 64, wn = (wid & 1) * 64;
    int s0 = tid, s1 = tid + 256;
    int r0 = s0 >> 2, c0 = (s0 & 3) ^ ((r0 >> 1) & 3);
    int r1 = s1 >> 2, c1 = (s1 & 3) ^ ((r1 >> 1) & 3);
    const bf16* A0 = A + (size_t)(bm + r0) * K + c0 * 8;
    const bf16* A1 = A + (size_t)(bm + r1) * K + c1 * 8;
    const bf16* B0 = BT + (size_t)(bn + r0) * K + c0 * 8;
    const bf16* B1 = BT + (size_t)(bn + r1) * K + c1 * 8;
    int rdc = quad ^ ((lid >> 1) & 3);
    g2l16(A0, As + s0 * 8);
    g2l16(B0, Bs + s0 * 8);
    g2l16(A1, As + s1 * 8);
    g2l16(B1, Bs + s1 * 8);
    for (int k0 = 0; k0 < K; k0 += 32) {
        __syncthreads();
        int cur = (k0 >> 5) & 1;
        if (k0 + 32 < K) {
            int nb = (cur ^ 1) * 4096;
            g2l16(A0 + k0 + 32, As + nb + s0 * 8);
            g2l16(B0 + k0 + 32, Bs + nb + s0 * 8);
            g2l16(A1 + k0 + 32, As + nb + s1 * 8);
            g2l16(B1 + k0 + 32, Bs + nb + s1 * 8);
        }
        const bf16* Ac = As + cur * 4096;
        const bf16* Bc = Bs + cur * 4096;
        bf16x8 af[4], bfr[4];
#pragma unroll
        for (int i = 0; i < 4; ++i) af[i]  = *(const bf16x8*)&Ac[(wm + i * 16 + lid) * 32 + rdc * 8];
#pragma unroll
        for (int j = 0; j < 4; ++j) bfr[j] = *(const bf16x8*)&Bc[(wn + j * 16 + lid) * 32 + rdc * 8];
#pragma unroll
        for (int i = 0; i < 4; ++i)
#pragma unroll
            for (int j = 0; j < 4; ++j)
                acc[i][j] = MFMA16(af[i], bfr[j], acc[i][j]);
    }
}

// ---------------- fused QKV projection -------------------------------------
__global__ __launch_bounds__(256) void gemm_qkv(const bf16* __restrict__ A,
                                                const bf16* __restrict__ WqT,
                                                const bf16* __restrict__ WkT,
                                                const bf16* __restrict__ WvT,
                                                const float* __restrict__ bq,
                                                const float* __restrict__ bk,
                                                const float* __restrict__ bv,
                                                bf16* __restrict__ qb,
                                                bf16* __restrict__ kb,
                                                bf16* __restrict__ vtb) {
    __shared__ bf16 As[2 * 128 * 32];
    __shared__ bf16 Bs[2 * 128 * 32];
    int which = blockIdx.x / 6;
    int bn = (blockIdx.x % 6) * 128;
    int bm = blockIdx.y * 128;
    const bf16* BT = (which == 0) ? WqT : (which == 1) ? WkT : WvT;
    const float* bias = (which == 0) ? bq : (which == 1) ? bk : bv;
    f32x4 acc[4][4] = {};
    gemm_core(A, BT, DM, bm, bn, As, Bs, acc);

    int tid = threadIdx.x, wid = tid >> 6, lane = tid & 63, quad = lane >> 4, lid = lane & 15;
    int wm = (wid >> 1) * 64, wn = (wid & 1) * 64;
    float sc = (which == 0) ? QSCALE : 1.f;   // fold softmax scale+log2e into Q
#pragma unroll
    for (int j = 0; j < 4; ++j) {
        int col = bn + wn + j * 16 + lid;
        float bb = bias[col];
        int hh = col >> 6, d = col & 63;
#pragma unroll
        for (int i = 0; i < 4; ++i) {
            int rowbase = bm + wm + i * 16 + quad * 4;
            int b = rowbase >> 11;
            int s0 = rowbase & 2047;
            if (which == 2) {
                ushort4 pk;
                pk.x = f2b_bits(acc[i][j][0] + bb);
                pk.y = f2b_bits(acc[i][j][1] + bb);
                pk.z = f2b_bits(acc[i][j][2] + bb);
                pk.w = f2b_bits(acc[i][j][3] + bb);
                *(ushort4*)&vtb[(((size_t)b * NH + hh) * DK + d) * SS + s0] = pk;
            } else {
                bf16* dst = which ? kb : qb;
#pragma unroll
                for (int r = 0; r < 4; ++r)
                    dst[(((size_t)b * NH + hh) * SS + (s0 + r)) * DK + d] = f2b((acc[i][j][r] + bb) * sc);
            }
        }
    }
}

// ---------------- 128x128 GEMM with epilogues (FFN1) ---------------
template <int EPI>
__global__ __launch_bounds__(256) void gemm_ep(const bf16* __restrict__ A,
                                               const bf16* __restrict__ BT,
                                               const float* __restrict__ bias,
                                               const float* __restrict__ res,
                                               void* __restrict__ outp,
                                               int N, int K) {
    __shared__ bf16 As[2 * 128 * 32];
    __shared__ bf16 Bs[2 * 128 * 32];
    int bm = blockIdx.y * 128, bn = blockIdx.x * 128;
    f32x4 acc[4][4] = {};
    gemm_core(A, BT, K, bm, bn, As, Bs, acc);

    int tid = threadIdx.x, wid = tid >> 6, lane = tid & 63, quad = lane >> 4, lid = lane & 15;
    int wm = (wid >> 1) * 64, wn = (wid & 1) * 64;
#pragma unroll
    for (int j = 0; j < 4; ++j) {
        int col = bn + wn + j * 16 + lid;
        float bb = bias[col];
#pragma unroll
        for (int i = 0; i < 4; ++i) {
#pragma unroll
            for (int r = 0; r < 4; ++r) {
                int row = bm + wm + i * 16 + quad * 4 + r;
                float v = acc[i][j][r] + bb;
                if (EPI == 2) {
                    ((float*)outp)[(size_t)row * N + col] = res[(size_t)row * N + col] + v;
                } else {
                    ((bf16*)outp)[(size_t)row * N + col] = f2b(fmaxf(v, 0.f));
                }
            }
        }
    }
}

// ---------------- 64x128 GEMM for N=768 outputs (Wo, FFN2) ------------------
// R4: in-block split-K, 512 threads (half h owns K-range [h*K/2,(h+1)*K/2)).
// R5: depth-2 staging pipeline over 3 LDS buffers with counted vmcnt (T4):
// iteration t waits vmcnt(3) (tile t's 3 DMAs done, tile t+1's still in
// flight; VMEM completes in per-thread issue order), raw s_barrier, issues
// tile t+2 into the buffer freed at t-1, computes tile t. Last iteration
// peels to vmcnt(0). This removes the vmcnt(0)-drain-per-iteration that
// left ~1200 cyc/iter of exposed L3/HBM latency in the R4 version (occupancy
// doubled in R4 but dur moved only 5% -> latency depth, not wave count, was
// the binder). sched_barrier(0) fences per rule #18.
template <int EPI>
__global__ __launch_bounds__(512) void gemm_ep64(const bf16* __restrict__ A,
                                                 const bf16* __restrict__ BT,
                                                 const float* __restrict__ bias,
                                                 const float* __restrict__ res,
                                                 void* __restrict__ outp,
                                                 int N, int K) {
    __shared__ char smem[73728];   // per-half: 3x(64x32 A + 128x32 B) bf16 = 36KB
    int tid = threadIdx.x;
    int half = tid >> 8, htid = tid & 255;
    bf16* As = (bf16*)smem + half * 6144;             // 3 bufs x 2048 bf16
    bf16* Bs = (bf16*)(smem + 24576) + half * 12288;  // 3 bufs x 4096 bf16
    int K2 = K >> 1, koff = half * K2;
    int nt = K2 >> 5;              // 32-wide K-steps per half
    int bm = blockIdx.y * 64, bn = blockIdx.x * 128;
    int wid = htid >> 6, lane = tid & 63, quad = lane >> 4, lid = lane & 15;
    int wm = (wid >> 1) * 32, wn = (wid & 1) * 64;
    f32x4 acc[2][4] = {};
    int ra = htid >> 2, ca = (htid & 3) ^ ((ra >> 1) & 3);
    int s0 = htid, s1 = htid + 256;
    int rb0 = s0 >> 2, cb0 = (s0 & 3) ^ ((rb0 >> 1) & 3);
    int rb1 = s1 >> 2, cb1 = (s1 & 3) ^ ((rb1 >> 1) & 3);
    const bf16* Ap = A + (size_t)(bm + ra) * K + koff + ca * 8;
    const bf16* B0 = BT + (size_t)(bn + rb0) * K + koff + cb0 * 8;
    const bf16* B1 = BT + (size_t)(bn + rb1) * K + koff + cb1 * 8;
    int rdc = quad ^ ((lid >> 1) & 3);

    // prologue: tiles 0 and 1 in flight (3 loads each)
    g2l16(Ap,      As + htid * 8);
    g2l16(B0,      Bs + s0 * 8);
    g2l16(B1,      Bs + s1 * 8);
    g2l16(Ap + 32, As + 2048 + htid * 8);
    g2l16(B0 + 32, Bs + 4096 + s0 * 8);
    g2l16(B1 + 32, Bs + 4096 + s1 * 8);

    int bcur = 0;
    for (int t = 0; t < nt; ++t) {
        __builtin_amdgcn_sched_barrier(0);
        if (t + 1 < nt) { ASM_VMCNT3; } else { ASM_VMCNT0; }
        __builtin_amdgcn_s_barrier();
        __builtin_amdgcn_sched_barrier(0);
        if (t + 2 < nt) {            // stage t+2 into the buffer freed at t-1
            int bi = bcur >= 1 ? bcur - 1 : 2;   // (bcur+2)%3
            int ko = (t + 2) * 32;
            g2l16(Ap + ko, As + bi * 2048 + htid * 8);
            g2l16(B0 + ko, Bs + bi * 4096 + s0 * 8);
            g2l16(B1 + ko, Bs + bi * 4096 + s1 * 8);
        }
        const bf16* Ac = As + bcur * 2048;
        const bf16* Bc = Bs + bcur * 4096;
        bf16x8 af[2], bfr[4];
#pragma unroll
        for (int i = 0; i < 2; ++i) af[i]  = *(const bf16x8*)&Ac[(wm + i * 16 + lid) * 32 + rdc * 8];
#pragma unroll
        for (int j = 0; j < 4; ++j) bfr[j] = *(const bf16x8*)&Bc[(wn + j * 16 + lid) * 32 + rdc * 8];
#pragma unroll
        for (int i = 0; i < 2; ++i)
#pragma unroll
            for (int j = 0; j < 4; ++j)
                acc[i][j] = MFMA16(af[i], bfr[j], acc[i][j]);
        bcur = bcur < 2 ? bcur + 1 : 0;
    }
    // ---- cross-half reduction through LDS (reuses As/Bs region) ----
    __syncthreads();               // all compute done block-wide; no DMAs outstanding
    float* red = (float*)smem;     // 256 threads x 32 floats = 32KB
    if (half == 1) {
#pragma unroll
        for (int i = 0; i < 2; ++i)
#pragma unroll
            for (int j = 0; j < 4; ++j) {
                int c = i * 4 + j;
                *(f32x4*)&red[htid * 32 + ((c ^ (htid & 7)) << 2)] = acc[i][j];
            }
    }
    __syncthreads();
    if (half == 0) {
#pragma unroll
        for (int i = 0; i < 2; ++i)
#pragma unroll
            for (int j = 0; j < 4; ++j) {
                int c = i * 4 + j;
                f32x4 o = *(const f32x4*)&red[htid * 32 + ((c ^ (htid & 7)) << 2)];
                acc[i][j] += o;
            }
#pragma unroll
        for (int j = 0; j < 4; ++j) {
            int col = bn + wn + j * 16 + lid;
            float bb = bias[col];
#pragma unroll
            for (int i = 0; i < 2; ++i) {
#pragma unroll
                for (int r = 0; r < 4; ++r) {
                    int row = bm + wm + i * 16 + quad * 4 + r;
                    float v = acc[i][j][r] + bb;
                    if (EPI == 2) {
                        ((float*)outp)[(size_t)row * N + col] = res[(size_t)row * N + col] + v;
                    } else {
                        ((bf16*)outp)[(size_t)row * N + col] = f2b(fmaxf(v, 0.f));
                    }
                }
            }
        }
    }
}

// ---------------- flash attention, k-chunk partials (KCH=2) -----------------
// R3: QB=128 -> two 16-row q-strips per wave. The per-strip instruction stream
// is R0's verified code; the strip loop reuses each kf/vf LDS fragment and the
// mask int4 for BOTH strips, halving LDS read amplification (36 -> 20 b128 per
// wave per 32 q-rows) and halving per-q K/V staging (L2) traffic. K/V staging
// is double-buffered with prefetch-after-barrier (one barrier per k-tile).
// grid (SS/128, 24, KCH) = 768 blocks; LDS 50KB -> exactly 3 blocks/CU.
__global__ __launch_bounds__(256) void attn_part(const bf16* __restrict__ qb,
                                                 const bf16* __restrict__ kb,
                                                 const bf16* __restrict__ vtb,
                                                 const int* __restrict__ mask,
                                                 bf16* __restrict__ part,
                                                 float* __restrict__ lws) {
    __shared__ bf16 Ks[2 * 64 * 64];
    __shared__ bf16 VTs[2 * 64 * 64];
    __shared__ bf16 Ps[128 * 72];   // [q][k], stride 72 -> b128 reads benign
    int bh = blockIdx.y;
    int b = bh / NH;
    int q0 = blockIdx.x * 128;
    int kc = blockIdx.z;
    const bf16* Kp = kb  + (size_t)bh * SS * DK;
    const bf16* VT = vtb + (size_t)bh * DK * SS;
    int tid = threadIdx.x, wid = tid >> 6, lane = tid & 63, quad = lane >> 4, lid = lane & 15;

    int s0 = tid, s1 = tid + 256;
    int r0 = s0 >> 3, c0 = (s0 & 7) ^ (r0 & 7);
    int r1 = s1 >> 3, c1 = (s1 & 7) ^ (r1 & 7);

    // Q fragments for both strips; same lane mapping serves as B-operand for S^T
    // strip u covers q rows q0 + wid*32 + u*16 + [0,16)
    bf16x8 qf0[2], qf1[2];
#pragma unroll
    for (int u = 0; u < 2; ++u) {
        const bf16* Qrow = qb + ((size_t)bh * SS + q0 + wid * 32 + u * 16 + lid) * DK;
        qf0[u] = *(const bf16x8*)&Qrow[quad * 8];
        qf1[u] = *(const bf16x8*)&Qrow[32 + quad * 8];
    }

    bf16x8 ones;
#pragma unroll
    for (int i = 0; i < 8; ++i) ones[i] = (short)0x3F80;   // bf16 1.0

    int rdc  = quad ^ (lid & 7);
    int rdc2 = rdc ^ 4;
    const int* mrow = mask + b * SS;

    f32x4 accv[2][4] = {};
    f32x4 accl[2] = {};

    int tbeg = kc * (SS / 64 / KCH), tend = (kc + 1) * (SS / 64 / KCH);

    // prologue: stage tile tbeg into buffer 0
    {
        int k0 = tbeg * 64;
        g2l16(Kp + (size_t)(k0 + r0) * DK + c0 * 8, Ks + s0 * 8);
        g2l16(Kp + (size_t)(k0 + r1) * DK + c1 * 8, Ks + s1 * 8);
        g2l16(VT + (size_t)r0 * SS + k0 + c0 * 8, VTs + s0 * 8);
        g2l16(VT + (size_t)r1 * SS + k0 + c1 * 8, VTs + s1 * 8);
    }

    int cur = 0;
    for (int t = tbeg; t < tend; ++t) {
        int k0 = t * 64;
        __syncthreads();   // buf[cur] staged (vmcnt drained); prev tile's reads done
        if (t + 1 < tend) {   // prefetch t+1 into alternate buffer; lands by next barrier
            int k0n = (t + 1) * 64;
            int nb = (cur ^ 1) * 4096;
            g2l16(Kp + (size_t)(k0n + r0) * DK + c0 * 8, Ks + nb + s0 * 8);
            g2l16(Kp + (size_t)(k0n + r1) * DK + c1 * 8, Ks + nb + s1 * 8);
            g2l16(VT + (size_t)r0 * SS + k0n + c0 * 8, VTs + nb + s0 * 8);
            g2l16(VT + (size_t)r1 * SS + k0n + c1 * 8, VTs + nb + s1 * 8);
        }
        const bf16* Kc  = Ks  + cur * 4096;
        const bf16* VTc = VTs + cur * 4096;

        // S^T: lane holds k = ns*16 + quad*4 + r, q = (strip base) + lid.
        // kf and the mask int4 are loaded once and reused for both strips.
#pragma unroll
        for (int ns = 0; ns < 4; ++ns) {
            bf16x8 kf0 = *(const bf16x8*)&Kc[(ns * 16 + lid) * 64 + rdc * 8];
            bf16x8 kf1 = *(const bf16x8*)&Kc[(ns * 16 + lid) * 64 + rdc2 * 8];
            int4 mk = *(const int4*)&mrow[k0 + ns * 16 + quad * 4];
#pragma unroll
            for (int u = 0; u < 2; ++u) {
                f32x4 st = {};
                st = MFMA16(kf0, qf0[u], st);
                st = MFMA16(kf1, qf1[u], st);
                float p0 = mk.x ? EXP2F(st[0]) : 0.f;
                float p1 = mk.y ? EXP2F(st[1]) : 0.f;
                float p2 = mk.z ? EXP2F(st[2]) : 0.f;
                float p3 = mk.w ? EXP2F(st[3]) : 0.f;
                __hip_bfloat162 h01 = __float22bfloat162_rn(make_float2(p0, p1));
                __hip_bfloat162 h23 = __float22bfloat162_rn(make_float2(p2, p3));
                uint2 pw;
                pw.x = *(unsigned int*)&h01;
                pw.y = *(unsigned int*)&h23;
                *(uint2*)&Ps[(wid * 32 + u * 16 + lid) * 72 + ns * 16 + quad * 4] = pw;
            }
        }

        // P A-frags (same-wave round trip, no barrier)
        bf16x8 pa0[2], pa1[2];
#pragma unroll
        for (int u = 0; u < 2; ++u) {
            pa0[u] = *(const bf16x8*)&Ps[(wid * 32 + u * 16 + lid) * 72 + quad * 8];
            pa1[u] = *(const bf16x8*)&Ps[(wid * 32 + u * 16 + lid) * 72 + 32 + quad * 8];
            // denominator via ones-MFMA: accl[u][r] = sum_k P[q][k]
            accl[u] = MFMA16(pa0[u], ones, accl[u]);
            accl[u] = MFMA16(pa1[u], ones, accl[u]);
        }

        // PV: vf fragments loaded once, reused for both strips
#pragma unroll
        for (int ds = 0; ds < 4; ++ds) {
            bf16x8 vf0 = *(const bf16x8*)&VTc[(ds * 16 + lid) * 64 + rdc * 8];
            bf16x8 vf1 = *(const bf16x8*)&VTc[(ds * 16 + lid) * 64 + rdc2 * 8];
#pragma unroll
            for (int u = 0; u < 2; ++u) {
                accv[u][ds] = MFMA16(pa0[u], vf0, accv[u][ds]);
                accv[u][ds] = MFMA16(pa1[u], vf1, accv[u][ds]);
            }
        }
        cur ^= 1;
    }

    bf16* pb = part + ((size_t)kc * (2 * NH) + bh) * DK * SS;
#pragma unroll
    for (int u = 0; u < 2; ++u) {
        if (lid == 0) {
#pragma unroll
            for (int r = 0; r < 4; ++r)
                lws[((size_t)kc * (2 * NH) + bh) * SS + q0 + wid * 32 + u * 16 + quad * 4 + r] = accl[u][r];
        }
        // raw partial context, transposed layout [kc][bh][d][s]: packed ushort4
        int qbase = q0 + wid * 32 + u * 16 + quad * 4;
#pragma unroll
        for (int ds = 0; ds < 4; ++ds) {
            int d = ds * 16 + lid;
            ushort4 pk;
            pk.x = f2b_bits(accv[u][ds][0]);
            pk.y = f2b_bits(accv[u][ds][1]);
            pk.z = f2b_bits(accv[u][ds][2]);
            pk.w = f2b_bits(accv[u][ds][3]);
            *(ushort4*)&pb[(size_t)d * SS + qbase] = pk;
        }
    }
}

// combine with LDS transpose: block per (64-q tile, bh).
// reads part[kc][bh][d][q] coalesced along q, writes ctx rows coalesced.
__global__ __launch_bounds__(256) void attn_combine(const bf16* __restrict__ part,
                                                    const float* __restrict__ lws,
                                                    bf16* __restrict__ ctx) {
    __shared__ float tile[64][66];
    __shared__ float linv[64];
    int bh = blockIdx.y;
    int b = bh / NH, h = bh % NH;
    int q0 = blockIdx.x * 64;
    int tid = threadIdx.x;

    if (tid < 64) {
        float l = 0.f;
#pragma unroll
        for (int kc = 0; kc < KCH; ++kc)
            l += lws[((size_t)kc * (2 * NH) + bh) * SS + q0 + tid];
        linv[tid] = 1.f / l;
    }

    // read phase: thread -> d = tid>>2, 16 q starting at (tid&3)*16
    int d = tid >> 2, qs = (tid & 3) * 16;
    const bf16* p0 = part + (((size_t)0 * (2 * NH) + bh) * DK + d) * SS + q0 + qs;
    const bf16* p1 = part + (((size_t)1 * (2 * NH) + bh) * DK + d) * SS + q0 + qs;
    bf16x8 a0 = *(const bf16x8*)p0;
    bf16x8 a1 = *(const bf16x8*)(p0 + 8);
    bf16x8 b0 = *(const bf16x8*)p1;
    bf16x8 b1 = *(const bf16x8*)(p1 + 8);
#pragma unroll
    for (int i = 0; i < 8; ++i) {
        tile[d][qs + i]     = b2f(((const bf16*)&a0)[i]) + b2f(((const bf16*)&b0)[i]);
        tile[d][qs + 8 + i] = b2f(((const bf16*)&a1)[i]) + b2f(((const bf16*)&b1)[i]);
    }
    __syncthreads();

    // write phase: thread -> q = tid>>2, 16 d starting at (tid&3)*16
    int q = tid >> 2, ds2 = (tid & 3) * 16;
    float rl = linv[q];
    unsigned int wv[8];
#pragma unroll
    for (int i = 0; i < 8; ++i) {
        __hip_bfloat162 hh = __float22bfloat162_rn(
            make_float2(tile[ds2 + 2 * i][q] * rl, tile[ds2 + 2 * i + 1][q] * rl));
        wv[i] = *(unsigned int*)&hh;
    }
    bf16* crow = ctx + (size_t)(b * SS + q0 + q) * DM + h * DK + ds2;
    uint4 u0 = {wv[0], wv[1], wv[2], wv[3]};
    uint4 u1 = {wv[4], wv[5], wv[6], wv[7]};
    *(uint4*)&crow[0] = u0;
    *(uint4*)&crow[8] = u1;
}

// ---------------- host launch ----------------------------------------------
extern "C" void kernel_launch(void* const* d_in, const int* in_sizes, int n_in,
                              void* d_out, int out_size, void* d_ws, size_t ws_size,
                              hipStream_t stream) {
    const float* x    = (const float*)d_in[0];
    const int*   mask = (const int*)d_in[1];
    const float* Wq   = (const float*)d_in[2];
    const float* bq   = (const float*)d_in[3];
    const float* Wk   = (const float*)d_in[4];
    const float* bk   = (const float*)d_in[5];
    const float* Wv   = (const float*)d_in[6];
    const float* bv   = (const float*)d_in[7];
    const float* Wo   = (const float*)d_in[8];
    const float* bo   = (const float*)d_in[9];
    const float* ln1a = (const float*)d_in[10];
    const float* ln1b = (const float*)d_in[11];
    const float* W1   = (const float*)d_in[12];
    const float* b1   = (const float*)d_in[13];
    const float* W2   = (const float*)d_in[14];
    const float* b2   = (const float*)d_in[15];
    const float* ln2a = (const float*)d_in[16];
    const float* ln2b = (const float*)d_in[17];
    float* out = (float*)d_out;

    char* w = (char*)d_ws;
    bf16* h   = (bf16*)w; w += (size_t)NTOK * DM * 2;
    bf16* qb  = (bf16*)w; w += (size_t)NTOK * DM * 2;
    bf16* kb  = (bf16*)w; w += (size_t)NTOK * DM * 2;
    bf16* vtb = (bf16*)w; w += (size_t)NTOK * DM * 2;
    bf16* ctx = (bf16*)w; w += (size_t)NTOK * DM * 2;
    bf16* h2  = (bf16*)w; w += (size_t)NTOK * DM * 2;
    bf16* ffa = (bf16*)w; w += (size_t)NTOK * DFF * 2;   // also attn partials (temporally disjoint)
    float* x1 = (float*)w; w += (size_t)NTOK * DM * 4;   // also attn l-partials (temporally disjoint)
    bf16* WqT = (bf16*)w; w += (size_t)DM * DM * 2;
    bf16* WkT = (bf16*)w; w += (size_t)DM * DM * 2;
    bf16* WvT = (bf16*)w; w += (size_t)DM * DM * 2;
    bf16* WoT = (bf16*)w; w += (size_t)DM * DM * 2;
    bf16* W1T = (bf16*)w; w += (size_t)DM * DFF * 2;
    bf16* W2T = (bf16*)w; w += (size_t)DM * DFF * 2;

    bf16*  part = ffa;          // KCH*2*NH*DK*SS*2 = 12.6 MB <= NTOK*DFF*2 (24 MB)
    float* lws  = x1;           // KCH*24*SS*4 = 384 KB < NTOK*DM*4

    transpose_all<<<6912, 256, 0, stream>>>(Wq, Wk, Wv, Wo, W1, W2,
                                            WqT, WkT, WvT, WoT, W1T, W2T);

    ln_fwd<<<NTOK / 4, 256, 0, stream>>>(x, ln1a, ln1b, h);
    gemm_qkv<<<dim3(18, 32), 256, 0, stream>>>(h, WqT, WkT, WvT, bq, bk, bv, qb, kb, vtb);
    attn_part<<<dim3(SS / 128, 2 * NH, KCH), 256, 0, stream>>>(qb, kb, vtb, mask, part, lws);
    attn_combine<<<dim3(SS / 64, 2 * NH), 256, 0, stream>>>(part, lws, ctx);
    gemm_ep64<2><<<dim3(6, 64), 512, 0, stream>>>(ctx, WoT, bo, x, (void*)x1, DM, DM);
    ln_fwd<<<NTOK / 4, 256, 0, stream>>>(x1, ln2a, ln2b, h2);
    gemm_ep<3><<<dim3(24, 32), 256, 0, stream>>>(h2, W1T, b1, nullptr, (void*)ffa, DFF, DM);
    gemm_ep64<2><<<dim3(6, 64), 512, 0, stream>>>(ffa, W2T, b2, x1, (void*)out, DM, DFF);
}

// Round 6
// 286.960 us; speedup vs baseline: 1.0204x; 1.0204x over previous
//
#include <hip/hip_runtime.h>
#include <hip/hip_bf16.h>
#include <stdint.h>

#define DM 768
#define DFF 3072
#define NH 12
#define DK 64
#define SS 2048
#define NTOK 4096   // B*S = 2*2048
#define KCH 2       // attention k-chunks: 16x24x2 = 768 blocks = exactly 3/CU

typedef __hip_bfloat16 bf16;
typedef short bf16x8 __attribute__((ext_vector_type(8)));
typedef float f32x4 __attribute__((ext_vector_type(4)));

#define MFMA16(a, b, c) __builtin_amdgcn_mfma_f32_16x16x32_bf16((a), (b), (c), 0, 0, 0)

// 0.125 (1/sqrt(Dk)) * log2(e), folded into the Q projection so attention uses exp2
#define QSCALE 0.18033688011112042f

#if __has_builtin(__builtin_amdgcn_exp2f)
#define EXP2F(x) __builtin_amdgcn_exp2f(x)   // raw v_exp_f32, no libm fixup
#else
#define EXP2F(x) exp2f(x)
#endif

static __device__ __forceinline__ bf16 f2b(float f) { return __float2bfloat16(f); }
static __device__ __forceinline__ unsigned short f2b_bits(float f) {
    bf16 h = __float2bfloat16(f);
    return *reinterpret_cast<unsigned short*>(&h);
}
static __device__ __forceinline__ float b2f(bf16 h) { return __bfloat162float(h); }

// async 16B global->LDS DMA. LDS dest must be wave-uniform base + lane*16.
static __device__ __forceinline__ void g2l16(const void* g, void* l) {
    __builtin_amdgcn_global_load_lds(
        (const __attribute__((address_space(1))) unsigned int*)g,
        (__attribute__((address_space(3))) unsigned int*)(uintptr_t)l,
        16, 0, 0);
}

// ---- fused: 6 weight transposes (blocks 0..6911) + LayerNorm1 (6912..7935) --
// The two parts have no data dependency; fusing removes one serial launch gap.
__global__ __launch_bounds__(256) void fused_pre(const float* Wq, const float* Wk,
                                                 const float* Wv, const float* Wo,
                                                 const float* W1, const float* W2,
                                                 bf16* WqT, bf16* WkT, bf16* WvT,
                                                 bf16* WoT, bf16* W1T, bf16* W2T,
                                                 const float* __restrict__ x,
                                                 const float* __restrict__ lg,
                                                 const float* __restrict__ lb,
                                                 bf16* __restrict__ hout) {
    int id = blockIdx.x;
    if (id >= 6912) {
        // ---- LayerNorm part (1024 blocks x 4 rows) ----
        int wid = threadIdx.x >> 6, lane = threadIdx.x & 63;
        int row = (id - 6912) * 4 + wid;
        const float* xr = x + (size_t)row * DM;
        float v[12];
        float s = 0.f;
#pragma unroll
        for (int i = 0; i < 12; ++i) { v[i] = xr[lane + i * 64]; s += v[i]; }
#pragma unroll
        for (int off = 32; off >= 1; off >>= 1) s += __shfl_xor(s, off);
        float mean = s * (1.f / 768.f);
        float s2 = 0.f;
#pragma unroll
        for (int i = 0; i < 12; ++i) { float d = v[i] - mean; s2 += d * d; }
#pragma unroll
        for (int off = 32; off >= 1; off >>= 1) s2 += __shfl_xor(s2, off);
        float rstd = 1.f / (sqrtf(s2 * (1.f / 767.f)) + 1e-6f);
        bf16* orow = hout + (size_t)row * DM;
#pragma unroll
        for (int i = 0; i < 12; ++i) {
            int c = lane + i * 64;
            orow[c] = f2b(lg[c] * (v[i] - mean) * rstd + lb[c]);
        }
        return;
    }
    // ---- transpose part (fp32->bf16, [K,N]->[N,K]) ----
    __shared__ float tile[32][33];
    const float* W; bf16* WT; int K, N, n0, k0;
    if (id < 2304) {            // Wq/Wk/Wv/Wo: 768x768, 24x24 blocks each
        int z = id / 576, r = id % 576;
        W  = (z == 0) ? Wq : (z == 1) ? Wk : (z == 2) ? Wv : Wo;
        WT = (z == 0) ? WqT : (z == 1) ? WkT : (z == 2) ? WvT : WoT;
        K = 768; N = 768; n0 = (r % 24) * 32; k0 = (r / 24) * 32;
    } else if (id < 4608) {     // W1: [768,3072] -> [3072,768]
        int r = id - 2304; W = W1; WT = W1T;
        K = 768; N = 3072; n0 = (r % 96) * 32; k0 = (r / 96) * 32;
    } else {                    // W2: [3072,768] -> [768,3072]
        int r = id - 4608; W = W2; WT = W2T;
        K = 3072; N = 768; n0 = (r % 24) * 32; k0 = (r / 24) * 32;
    }
    int tx = threadIdx.x & 31, ty = threadIdx.x >> 5;
#pragma unroll
    for (int r = ty; r < 32; r += 8)
        tile[r][tx] = W[(size_t)(k0 + r) * N + n0 + tx];
    __syncthreads();
#pragma unroll
    for (int r = ty; r < 32; r += 8)
        WT[(size_t)(n0 + r) * K + k0 + tx] = f2b(tile[tx][r]);
}

// ---------------- LayerNorm (unbiased var, eps on std) --------
__global__ __launch_bounds__(256) void ln_fwd(const float* __restrict__ x,
                                              const float* __restrict__ g,
                                              const float* __restrict__ be,
                                              bf16* __restrict__ out) {
    int wid = threadIdx.x >> 6, lane = threadIdx.x & 63;
    int row = blockIdx.x * 4 + wid;
    const float* xr = x + (size_t)row * DM;
    float v[12];
    float s = 0.f;
#pragma unroll
    for (int i = 0; i < 12; ++i) { v[i] = xr[lane + i * 64]; s += v[i]; }
#pragma unroll
    for (int off = 32; off >= 1; off >>= 1) s += __shfl_xor(s, off);
    float mean = s * (1.f / 768.f);
    float s2 = 0.f;
#pragma unroll
    for (int i = 0; i < 12; ++i) { float d = v[i] - mean; s2 += d * d; }
#pragma unroll
    for (int off = 32; off >= 1; off >>= 1) s2 += __shfl_xor(s2, off);
    float rstd = 1.f / (sqrtf(s2 * (1.f / 767.f)) + 1e-6f);
    bf16* orow = out + (size_t)row * DM;
#pragma unroll
    for (int i = 0; i < 12; ++i) {
        int c = lane + i * 64;
        orow[c] = f2b(g[c] * (v[i] - mean) * rstd + be[c]);
    }
}

// ---------------- 128x128 GEMM core, BK=32, dbuf, prefetch-after-barrier -----
// (R7-proven best) 16B chunk c of row r at phys chunk c ^ ((r>>1)&3).
__device__ __forceinline__ void gemm_core(const bf16* __restrict__ A,
                                          const bf16* __restrict__ BT,
                                          int K, int bm, int bn,
                                          bf16* As, bf16* Bs,   // each 2*128*32
                                          f32x4 acc[4][4]) {
    int tid = threadIdx.x;
    int lane = tid & 63, quad = lane >> 4, lid = lane & 15;
    int wid = tid >> 6;
    int wm = (wid >> 1) * 64, wn = (wid & 1) * 64;
    int s0 = tid, s1 = tid + 256;
    int r0 = s0 >> 2, c0 = (s0 & 3) ^ ((r0 >> 1) & 3);
    int r1 = s1 >> 2, c1 = (s1 & 3) ^ ((r1 >> 1) & 3);
    const bf16* A0 = A + (size_t)(bm + r0) * K + c0 * 8;
    const bf16* A1 = A + (size_t)(bm + r1) * K + c1 * 8;
    const bf16* B0 = BT + (size_t)(bn + r0) * K + c0 * 8;
    const bf16* B1 = BT + (size_t)(bn + r1) * K + c1 * 8;
    int rdc = quad ^ ((lid >> 1) & 3);
    g2l16(A0, As + s0 * 8);
    g2l16(B0, Bs + s0 * 8);
    g2l16(A1, As + s1 * 8);
    g2l16(B1, Bs + s1 * 8);
    for (int k0 = 0; k0 < K; k0 += 32) {
        __syncthreads();
        int cur = (k0 >> 5) & 1;
        if (k0 + 32 < K) {
            int nb = (cur ^ 1) * 4096;
            g2l16(A0 + k0 + 32, As + nb + s0 * 8);
            g2l16(B0 + k0 + 32, Bs + nb + s0 * 8);
            g2l16(A1 + k0 + 32, As + nb + s1 * 8);
            g2l16(B1 + k0 + 32, Bs + nb + s1 * 8);
        }
        const bf16* Ac = As + cur * 4096;
        const bf16* Bc = Bs + cur * 4096;
        bf16x8 af[4], bfr[4];
#pragma unroll
        for (int i = 0; i < 4; ++i) af[i]  = *(const bf16x8*)&Ac[(wm + i * 16 + lid) * 32 + rdc * 8];
#pragma unroll
        for (int j = 0; j < 4; ++j) bfr[j] = *(const bf16x8*)&Bc[(wn + j * 16 + lid) * 32 + rdc * 8];
#pragma unroll
        for (int i = 0; i < 4; ++i)
#pragma unroll
            for (int j = 0; j < 4; ++j)
                acc[i][j] = MFMA16(af[i], bfr[j], acc[i][j]);
    }
}

// ---------------- fused QKV projection -------------------------------------
__global__ __launch_bounds__(256) void gemm_qkv(const bf16* __restrict__ A,
                                                const bf16* __restrict__ WqT,
                                                const bf16* __restrict__ WkT,
                                                const bf16* __restrict__ WvT,
                                                const float* __restrict__ bq,
                                                const float* __restrict__ bk,
                                                const float* __restrict__ bv,
                                                bf16* __restrict__ qb,
                                                bf16* __restrict__ kb,
                                                bf16* __restrict__ vtb) {
    __shared__ bf16 As[2 * 128 * 32];
    __shared__ bf16 Bs[2 * 128 * 32];
    int which = blockIdx.x / 6;
    int bn = (blockIdx.x % 6) * 128;
    int bm = blockIdx.y * 128;
    const bf16* BT = (which == 0) ? WqT : (which == 1) ? WkT : WvT;
    const float* bias = (which == 0) ? bq : (which == 1) ? bk : bv;
    f32x4 acc[4][4] = {};
    gemm_core(A, BT, DM, bm, bn, As, Bs, acc);

    int tid = threadIdx.x, wid = tid >> 6, lane = tid & 63, quad = lane >> 4, lid = lane & 15;
    int wm = (wid >> 1) * 64, wn = (wid & 1) * 64;
    float sc = (which == 0) ? QSCALE : 1.f;   // fold softmax scale+log2e into Q
#pragma unroll
    for (int j = 0; j < 4; ++j) {
        int col = bn + wn + j * 16 + lid;
        float bb = bias[col];
        int hh = col >> 6, d = col & 63;
#pragma unroll
        for (int i = 0; i < 4; ++i) {
            int rowbase = bm + wm + i * 16 + quad * 4;
            int b = rowbase >> 11;
            int s0 = rowbase & 2047;
            if (which == 2) {
                ushort4 pk;
                pk.x = f2b_bits(acc[i][j][0] + bb);
                pk.y = f2b_bits(acc[i][j][1] + bb);
                pk.z = f2b_bits(acc[i][j][2] + bb);
                pk.w = f2b_bits(acc[i][j][3] + bb);
                *(ushort4*)&vtb[(((size_t)b * NH + hh) * DK + d) * SS + s0] = pk;
            } else {
                bf16* dst = which ? kb : qb;
#pragma unroll
                for (int r = 0; r < 4; ++r)
                    dst[(((size_t)b * NH + hh) * SS + (s0 + r)) * DK + d] = f2b((acc[i][j][r] + bb) * sc);
            }
        }
    }
}

// ---------------- 128x128 GEMM with epilogues (FFN1) ---------------
template <int EPI>
__global__ __launch_bounds__(256) void gemm_ep(const bf16* __restrict__ A,
                                               const bf16* __restrict__ BT,
                                               const float* __restrict__ bias,
                                               const float* __restrict__ res,
                                               void* __restrict__ outp,
                                               int N, int K) {
    __shared__ bf16 As[2 * 128 * 32];
    __shared__ bf16 Bs[2 * 128 * 32];
    int bm = blockIdx.y * 128, bn = blockIdx.x * 128;
    f32x4 acc[4][4] = {};
    gemm_core(A, BT, K, bm, bn, As, Bs, acc);

    int tid = threadIdx.x, wid = tid >> 6, lane = tid & 63, quad = lane >> 4, lid = lane & 15;
    int wm = (wid >> 1) * 64, wn = (wid & 1) * 64;
#pragma unroll
    for (int j = 0; j < 4; ++j) {
        int col = bn + wn + j * 16 + lid;
        float bb = bias[col];
#pragma unroll
        for (int i = 0; i < 4; ++i) {
#pragma unroll
            for (int r = 0; r < 4; ++r) {
                int row = bm + wm + i * 16 + quad * 4 + r;
                float v = acc[i][j][r] + bb;
                if (EPI == 2) {
                    ((float*)outp)[(size_t)row * N + col] = res[(size_t)row * N + col] + v;
                } else {
                    ((bf16*)outp)[(size_t)row * N + col] = f2b(fmaxf(v, 0.f));
                }
            }
        }
    }
}

// ---------------- 64x96 GEMM for N=768 outputs (Wo, FFN2) -------------------
// R6: balanced grid. 64x128 tiles gave grid=384 on 256 CUs -> half the CUs run
// 2 blocks, half 1 (makespan 2T vs ideal 1.5T, ~33% waste; counters all-low).
// R4 (2x waves) and R5 (depth-2 vmcnt pipeline) were both null -> neither wave
// count nor pipeline depth was the binder. 64x96 tiles -> grid (8,64) = 512
// blocks = exactly 2/CU, balanced. Same proven depth-1 dbuf core, 256 thr,
// per-wave 32x48 (af2+bfr3 ds_reads, 6 MFMA). LDS 20KB.
template <int EPI>
__global__ __launch_bounds__(256) void gemm_ep96(const bf16* __restrict__ A,
                                                 const bf16* __restrict__ BT,
                                                 const float* __restrict__ bias,
                                                 const float* __restrict__ res,
                                                 void* __restrict__ outp,
                                                 int N, int K) {
    __shared__ bf16 As[2 * 64 * 32];    // 8 KB
    __shared__ bf16 Bs[2 * 96 * 32];    // 12 KB
    int bm = blockIdx.y * 64, bn = blockIdx.x * 96;
    int tid = threadIdx.x, wid = tid >> 6, lane = tid & 63, quad = lane >> 4, lid = lane & 15;
    int wm = (wid >> 1) * 32, wn = (wid & 1) * 48;
    f32x4 acc[2][3] = {};
    int ra = tid >> 2, ca = (tid & 3) ^ ((ra >> 1) & 3);
    int s0 = tid, s1 = tid + 256;            // B slots; s1 valid for tid<128 (rows 64..95)
    int rb0 = s0 >> 2, cb0 = (s0 & 3) ^ ((rb0 >> 1) & 3);
    int rb1 = s1 >> 2, cb1 = (s1 & 3) ^ ((rb1 >> 1) & 3);
    const bf16* Ap = A + (size_t)(bm + ra) * K + ca * 8;
    const bf16* B0 = BT + (size_t)(bn + rb0) * K + cb0 * 8;
    const bf16* B1 = BT + (size_t)(bn + rb1) * K + cb1 * 8;
    int rdc = quad ^ ((lid >> 1) & 3);
    bool doB1 = tid < 128;                   // wave-uniform (waves 0,1)
    g2l16(Ap, As + tid * 8);
    g2l16(B0, Bs + s0 * 8);
    if (doB1) g2l16(B1, Bs + s1 * 8);
    for (int k0 = 0; k0 < K; k0 += 32) {
        __syncthreads();
        int cur = (k0 >> 5) & 1;
        if (k0 + 32 < K) {
            g2l16(Ap + k0 + 32, As + (cur ^ 1) * 2048 + tid * 8);
            g2l16(B0 + k0 + 32, Bs + (cur ^ 1) * 3072 + s0 * 8);
            if (doB1) g2l16(B1 + k0 + 32, Bs + (cur ^ 1) * 3072 + s1 * 8);
        }
        const bf16* Ac = As + cur * 2048;
        const bf16* Bc = Bs + cur * 3072;
        bf16x8 af[2], bfr[3];
#pragma unroll
        for (int i = 0; i < 2; ++i) af[i]  = *(const bf16x8*)&Ac[(wm + i * 16 + lid) * 32 + rdc * 8];
#pragma unroll
        for (int j = 0; j < 3; ++j) bfr[j] = *(const bf16x8*)&Bc[(wn + j * 16 + lid) * 32 + rdc * 8];
#pragma unroll
        for (int i = 0; i < 2; ++i)
#pragma unroll
            for (int j = 0; j < 3; ++j)
                acc[i][j] = MFMA16(af[i], bfr[j], acc[i][j]);
    }
#pragma unroll
    for (int j = 0; j < 3; ++j) {
        int col = bn + wn + j * 16 + lid;
        float bb = bias[col];
#pragma unroll
        for (int i = 0; i < 2; ++i) {
#pragma unroll
            for (int r = 0; r < 4; ++r) {
                int row = bm + wm + i * 16 + quad * 4 + r;
                float v = acc[i][j][r] + bb;
                if (EPI == 2) {
                    ((float*)outp)[(size_t)row * N + col] = res[(size_t)row * N + col] + v;
                } else {
                    ((bf16*)outp)[(size_t)row * N + col] = f2b(fmaxf(v, 0.f));
                }
            }
        }
    }
}

// ---------------- flash attention, k-chunk partials (KCH=2) -----------------
// R3: QB=128, two 16-row q-strips per wave (kf/vf/mask reused across strips).
// R6: block-uniform mask fast-path — one __syncthreads_and over the block's
// 1024 mask ints; when all-set (the common case) skip all per-tile mask int4
// loads and the 64 cndmasks per wave-tile (VALU was the hottest pipe at 43%).
// grid (SS/128, 24, KCH) = 768 blocks; LDS 50KB -> exactly 3 blocks/CU.
__global__ __launch_bounds__(256) void attn_part(const bf16* __restrict__ qb,
                                                 const bf16* __restrict__ kb,
                                                 const bf16* __restrict__ vtb,
                                                 const int* __restrict__ mask,
                                                 bf16* __restrict__ part,
                                                 float* __restrict__ lws) {
    __shared__ bf16 Ks[2 * 64 * 64];
    __shared__ bf16 VTs[2 * 64 * 64];
    __shared__ bf16 Ps[128 * 72];   // [q][k], stride 72 -> b128 reads benign
    int bh = blockIdx.y;
    int b = bh / NH;
    int q0 = blockIdx.x * 128;
    int kc = blockIdx.z;
    const bf16* Kp = kb  + (size_t)bh * SS * DK;
    const bf16* VT = vtb + (size_t)bh * DK * SS;
    int tid = threadIdx.x, wid = tid >> 6, lane = tid & 63, quad = lane >> 4, lid = lane & 15;

    int s0 = tid, s1 = tid + 256;
    int r0 = s0 >> 3, c0 = (s0 & 7) ^ (r0 & 7);
    int r1 = s1 >> 3, c1 = (s1 & 7) ^ (r1 & 7);

    const int* mrow = mask + b * SS;
    int tbeg = kc * (SS / 64 / KCH), tend = (kc + 1) * (SS / 64 / KCH);

    // block-uniform mask check over this block's k-range (1024 ints = 256xint4)
    int myfull;
    {
        const int4* m4 = (const int4*)(mrow + tbeg * 64);
        int4 mm = m4[tid];
        myfull = (mm.x != 0) & (mm.y != 0) & (mm.z != 0) & (mm.w != 0);
    }
    int blockfull = __syncthreads_and(myfull);

    // Q fragments for both strips; same lane mapping serves as B-operand for S^T
    // strip u covers q rows q0 + wid*32 + u*16 + [0,16)
    bf16x8 qf0[2], qf1[2];
#pragma unroll
    for (int u = 0; u < 2; ++u) {
        const bf16* Qrow = qb + ((size_t)bh * SS + q0 + wid * 32 + u * 16 + lid) * DK;
        qf0[u] = *(const bf16x8*)&Qrow[quad * 8];
        qf1[u] = *(const bf16x8*)&Qrow[32 + quad * 8];
    }

    bf16x8 ones;
#pragma unroll
    for (int i = 0; i < 8; ++i) ones[i] = (short)0x3F80;   // bf16 1.0

    int rdc  = quad ^ (lid & 7);
    int rdc2 = rdc ^ 4;

    f32x4 accv[2][4] = {};
    f32x4 accl[2] = {};

    // prologue: stage tile tbeg into buffer 0
    {
        int k0 = tbeg * 64;
        g2l16(Kp + (size_t)(k0 + r0) * DK + c0 * 8, Ks + s0 * 8);
        g2l16(Kp + (size_t)(k0 + r1) * DK + c1 * 8, Ks + s1 * 8);
        g2l16(VT + (size_t)r0 * SS + k0 + c0 * 8, VTs + s0 * 8);
        g2l16(VT + (size_t)r1 * SS + k0 + c1 * 8, VTs + s1 * 8);
    }

    int cur = 0;
    for (int t = tbeg; t < tend; ++t) {
        int k0 = t * 64;
        __syncthreads();   // buf[cur] staged (vmcnt drained); prev tile's reads done
        if (t + 1 < tend) {   // prefetch t+1 into alternate buffer; lands by next barrier
            int k0n = (t + 1) * 64;
            int nb = (cur ^ 1) * 4096;
            g2l16(Kp + (size_t)(k0n + r0) * DK + c0 * 8, Ks + nb + s0 * 8);
            g2l16(Kp + (size_t)(k0n + r1) * DK + c1 * 8, Ks + nb + s1 * 8);
            g2l16(VT + (size_t)r0 * SS + k0n + c0 * 8, VTs + nb + s0 * 8);
            g2l16(VT + (size_t)r1 * SS + k0n + c1 * 8, VTs + nb + s1 * 8);
        }
        const bf16* Kc  = Ks  + cur * 4096;
        const bf16* VTc = VTs + cur * 4096;

        // S^T: lane holds k = ns*16 + quad*4 + r, q = (strip base) + lid.
        // kf reused for both strips.
#pragma unroll
        for (int ns = 0; ns < 4; ++ns) {
            bf16x8 kf0 = *(const bf16x8*)&Kc[(ns * 16 + lid) * 64 + rdc * 8];
            bf16x8 kf1 = *(const bf16x8*)&Kc[(ns * 16 + lid) * 64 + rdc2 * 8];
#pragma unroll
            for (int u = 0; u < 2; ++u) {
                f32x4 st = {};
                st = MFMA16(kf0, qf0[u], st);
                st = MFMA16(kf1, qf1[u], st);
                float p0, p1, p2, p3;
                if (blockfull) {
                    p0 = EXP2F(st[0]);
                    p1 = EXP2F(st[1]);
                    p2 = EXP2F(st[2]);
                    p3 = EXP2F(st[3]);
                } else {
                    int4 mk = *(const int4*)&mrow[k0 + ns * 16 + quad * 4];
                    p0 = mk.x ? EXP2F(st[0]) : 0.f;
                    p1 = mk.y ? EXP2F(st[1]) : 0.f;
                    p2 = mk.z ? EXP2F(st[2]) : 0.f;
                    p3 = mk.w ? EXP2F(st[3]) : 0.f;
                }
                __hip_bfloat162 h01 = __float22bfloat162_rn(make_float2(p0, p1));
                __hip_bfloat162 h23 = __float22bfloat162_rn(make_float2(p2, p3));
                uint2 pw;
                pw.x = *(unsigned int*)&h01;
                pw.y = *(unsigned int*)&h23;
                *(uint2*)&Ps[(wid * 32 + u * 16 + lid) * 72 + ns * 16 + quad * 4] = pw;
            }
        }

        // P A-frags (same-wave round trip, no barrier)
        bf16x8 pa0[2], pa1[2];
#pragma unroll
        for (int u = 0; u < 2; ++u) {
            pa0[u] = *(const bf16x8*)&Ps[(wid * 32 + u * 16 + lid) * 72 + quad * 8];
            pa1[u] = *(const bf16x8*)&Ps[(wid * 32 + u * 16 + lid) * 72 + 32 + quad * 8];
            // denominator via ones-MFMA: accl[u][r] = sum_k P[q][k]
            accl[u] = MFMA16(pa0[u], ones, accl[u]);
            accl[u] = MFMA16(pa1[u], ones, accl[u]);
        }

        // PV: vf fragments loaded once, reused for both strips
#pragma unroll
        for (int ds = 0; ds < 4; ++ds) {
            bf16x8 vf0 = *(const bf16x8*)&VTc[(ds * 16 + lid) * 64 + rdc * 8];
            bf16x8 vf1 = *(const bf16x8*)&VTc[(ds * 16 + lid) * 64 + rdc2 * 8];
#pragma unroll
            for (int u = 0; u < 2; ++u) {
                accv[u][ds] = MFMA16(pa0[u], vf0, accv[u][ds]);
                accv[u][ds] = MFMA16(pa1[u], vf1, accv[u][ds]);
            }
        }
        cur ^= 1;
    }

    bf16* pb = part + ((size_t)kc * (2 * NH) + bh) * DK * SS;
#pragma unroll
    for (int u = 0; u < 2; ++u) {
        if (lid == 0) {
#pragma unroll
            for (int r = 0; r < 4; ++r)
                lws[((size_t)kc * (2 * NH) + bh) * SS + q0 + wid * 32 + u * 16 + quad * 4 + r] = accl[u][r];
        }
        // raw partial context, transposed layout [kc][bh][d][s]: packed ushort4
        int qbase = q0 + wid * 32 + u * 16 + quad * 4;
#pragma unroll
        for (int ds = 0; ds < 4; ++ds) {
            int d = ds * 16 + lid;
            ushort4 pk;
            pk.x = f2b_bits(accv[u][ds][0]);
            pk.y = f2b_bits(accv[u][ds][1]);
            pk.z = f2b_bits(accv[u][ds][2]);
            pk.w = f2b_bits(accv[u][ds][3]);
            *(ushort4*)&pb[(size_t)d * SS + qbase] = pk;
        }
    }
}

// combine with LDS transpose: block per (64-q tile, bh).
// reads part[kc][bh][d][q] coalesced along q, writes ctx rows coalesced.
__global__ __launch_bounds__(256) void attn_combine(const bf16* __restrict__ part,
                                                    const float* __restrict__ lws,
                                                    bf16* __restrict__ ctx) {
    __shared__ float tile[64][66];
    __shared__ float linv[64];
    int bh = blockIdx.y;
    int b = bh / NH, h = bh % NH;
    int q0 = blockIdx.x * 64;
    int tid = threadIdx.x;

    if (tid < 64) {
        float l = 0.f;
#pragma unroll
        for (int kc = 0; kc < KCH; ++kc)
            l += lws[((size_t)kc * (2 * NH) + bh) * SS + q0 + tid];
        linv[tid] = 1.f / l;
    }

    // read phase: thread -> d = tid>>2, 16 q starting at (tid&3)*16
    int d = tid >> 2, qs = (tid & 3) * 16;
    const bf16* p0 = part + (((size_t)0 * (2 * NH) + bh) * DK + d) * SS + q0 + qs;
    const bf16* p1 = part + (((size_t)1 * (2 * NH) + bh) * DK + d) * SS + q0 + qs;
    bf16x8 a0 = *(const bf16x8*)p0;
    bf16x8 a1 = *(const bf16x8*)(p0 + 8);
    bf16x8 b0 = *(const bf16x8*)p1;
    bf16x8 b1 = *(const bf16x8*)(p1 + 8);
#pragma unroll
    for (int i = 0; i < 8; ++i) {
        tile[d][qs + i]     = b2f(((const bf16*)&a0)[i]) + b2f(((const bf16*)&b0)[i]);
        tile[d][qs + 8 + i] = b2f(((const bf16*)&a1)[i]) + b2f(((const bf16*)&b1)[i]);
    }
    __syncthreads();

    // write phase: thread -> q = tid>>2, 16 d starting at (tid&3)*16
    int q = tid >> 2, ds2 = (tid & 3) * 16;
    float rl = linv[q];
    unsigned int wv[8];
#pragma unroll
    for (int i = 0; i < 8; ++i) {
        __hip_bfloat162 hh = __float22bfloat162_rn(
            make_float2(tile[ds2 + 2 * i][q] * rl, tile[ds2 + 2 * i + 1][q] * rl));
        wv[i] = *(unsigned int*)&hh;
    }
    bf16* crow = ctx + (size_t)(b * SS + q0 + q) * DM + h * DK + ds2;
    uint4 u0 = {wv[0], wv[1], wv[2], wv[3]};
    uint4 u1 = {wv[4], wv[5], wv[6], wv[7]};
    *(uint4*)&crow[0] = u0;
    *(uint4*)&crow[8] = u1;
}

// ---------------- host launch ----------------------------------------------
extern "C" void kernel_launch(void* const* d_in, const int* in_sizes, int n_in,
                              void* d_out, int out_size, void* d_ws, size_t ws_size,
                              hipStream_t stream) {
    const float* x    = (const float*)d_in[0];
    const int*   mask = (const int*)d_in[1];
    const float* Wq   = (const float*)d_in[2];
    const float* bq   = (const float*)d_in[3];
    const float* Wk   = (const float*)d_in[4];
    const float* bk   = (const float*)d_in[5];
    const float* Wv   = (const float*)d_in[6];
    const float* bv   = (const float*)d_in[7];
    const float* Wo   = (const float*)d_in[8];
    const float* bo   = (const float*)d_in[9];
    const float* ln1a = (const float*)d_in[10];
    const float* ln1b = (const float*)d_in[11];
    const float* W1   = (const float*)d_in[12];
    const float* b1   = (const float*)d_in[13];
    const float* W2   = (const float*)d_in[14];
    const float* b2   = (const float*)d_in[15];
    const float* ln2a = (const float*)d_in[16];
    const float* ln2b = (const float*)d_in[17];
    float* out = (float*)d_out;

    char* w = (char*)d_ws;
    bf16* h   = (bf16*)w; w += (size_t)NTOK * DM * 2;
    bf16* qb  = (bf16*)w; w += (size_t)NTOK * DM * 2;
    bf16* kb  = (bf16*)w; w += (size_t)NTOK * DM * 2;
    bf16* vtb = (bf16*)w; w += (size_t)NTOK * DM * 2;
    bf16* ctx = (bf16*)w; w += (size_t)NTOK * DM * 2;
    bf16* h2  = (bf16*)w; w += (size_t)NTOK * DM * 2;
    bf16* ffa = (bf16*)w; w += (size_t)NTOK * DFF * 2;   // also attn partials (temporally disjoint)
    float* x1 = (float*)w; w += (size_t)NTOK * DM * 4;   // also attn l-partials (temporally disjoint)
    bf16* WqT = (bf16*)w; w += (size_t)DM * DM * 2;
    bf16* WkT = (bf16*)w; w += (size_t)DM * DM * 2;
    bf16* WvT = (bf16*)w; w += (size_t)DM * DM * 2;
    bf16* WoT = (bf16*)w; w += (size_t)DM * DM * 2;
    bf16* W1T = (bf16*)w; w += (size_t)DM * DFF * 2;
    bf16* W2T = (bf16*)w; w += (size_t)DM * DFF * 2;

    bf16*  part = ffa;          // KCH*2*NH*DK*SS*2 = 12.6 MB <= NTOK*DFF*2 (24 MB)
    float* lws  = x1;           // KCH*24*SS*4 = 384 KB < NTOK*DM*4

    fused_pre<<<6912 + NTOK / 4, 256, 0, stream>>>(Wq, Wk, Wv, Wo, W1, W2,
                                                   WqT, WkT, WvT, WoT, W1T, W2T,
                                                   x, ln1a, ln1b, h);
    gemm_qkv<<<dim3(18, 32), 256, 0, stream>>>(h, WqT, WkT, WvT, bq, bk, bv, qb, kb, vtb);
    attn_part<<<dim3(SS / 128, 2 * NH, KCH), 256, 0, stream>>>(qb, kb, vtb, mask, part, lws);
    attn_combine<<<dim3(SS / 64, 2 * NH), 256, 0, stream>>>(part, lws, ctx);
    gemm_ep96<2><<<dim3(8, 64), 256, 0, stream>>>(ctx, WoT, bo, x, (void*)x1, DM, DM);
    ln_fwd<<<NTOK / 4, 256, 0, stream>>>(x1, ln2a, ln2b, h2);
    gemm_ep<3><<<dim3(24, 32), 256, 0, stream>>>(h2, W1T, b1, nullptr, (void*)ffa, DFF, DM);
    gemm_ep96<2><<<dim3(8, 64), 256, 0, stream>>>(ffa, W2T, b2, x1, (void*)out, DM, DFF);
}

// Round 7
// 272.819 us; speedup vs baseline: 1.0733x; 1.0518x over previous
//
#include <hip/hip_runtime.h>
#include <hip/hip_bf16.h>
#include <stdint.h>

#define DM 768
#define DFF 3072
#define NH 12
#define DK 64
#define SS 2048
#define NTOK 4096   // B*S = 2*2048
#define KCH 2       // attention k-chunks: 16x24x2 = 768 blocks = exactly 3/CU

typedef __hip_bfloat16 bf16;
typedef short bf16x8 __attribute__((ext_vector_type(8)));
typedef float f32x4 __attribute__((ext_vector_type(4)));

#define MFMA16(a, b, c) __builtin_amdgcn_mfma_f32_16x16x32_bf16((a), (b), (c), 0, 0, 0)

// 0.125 (1/sqrt(Dk)) * log2(e), folded into the Q projection so attention uses exp2
#define QSCALE 0.18033688011112042f

#if __has_builtin(__builtin_amdgcn_exp2f)
#define EXP2F(x) __builtin_amdgcn_exp2f(x)   // raw v_exp_f32, no libm fixup
#else
#define EXP2F(x) exp2f(x)
#endif

static __device__ __forceinline__ bf16 f2b(float f) { return __float2bfloat16(f); }
static __device__ __forceinline__ unsigned short f2b_bits(float f) {
    bf16 h = __float2bfloat16(f);
    return *reinterpret_cast<unsigned short*>(&h);
}
static __device__ __forceinline__ float b2f(bf16 h) { return __bfloat162float(h); }

// async 16B global->LDS DMA. LDS dest must be wave-uniform base + lane*16.
static __device__ __forceinline__ void g2l16(const void* g, void* l) {
    __builtin_amdgcn_global_load_lds(
        (const __attribute__((address_space(1))) unsigned int*)g,
        (__attribute__((address_space(3))) unsigned int*)(uintptr_t)l,
        16, 0, 0);
}

// bijective XCD-chunk swizzle (T1): grid must be a multiple of 8.
// round-robin dispatch (bid%8 = XCD) -> each XCD sees a CONTIGUOUS wg chunk.
static __device__ __forceinline__ int xcd_swz(int bid, int nwg) {
    int q = nwg >> 3;
    return (bid & 7) * q + (bid >> 3);
}

// ---- fused: 6 weight transposes (blocks 0..6911) + LayerNorm1 (6912..7935) --
__global__ __launch_bounds__(256) void fused_pre(const float* Wq, const float* Wk,
                                                 const float* Wv, const float* Wo,
                                                 const float* W1, const float* W2,
                                                 bf16* WqT, bf16* WkT, bf16* WvT,
                                                 bf16* WoT, bf16* W1T, bf16* W2T,
                                                 const float* __restrict__ x,
                                                 const float* __restrict__ lg,
                                                 const float* __restrict__ lb,
                                                 bf16* __restrict__ hout) {
    int id = blockIdx.x;
    if (id >= 6912) {
        // ---- LayerNorm part (1024 blocks x 4 rows) ----
        int wid = threadIdx.x >> 6, lane = threadIdx.x & 63;
        int row = (id - 6912) * 4 + wid;
        const float* xr = x + (size_t)row * DM;
        float v[12];
        float s = 0.f;
#pragma unroll
        for (int i = 0; i < 12; ++i) { v[i] = xr[lane + i * 64]; s += v[i]; }
#pragma unroll
        for (int off = 32; off >= 1; off >>= 1) s += __shfl_xor(s, off);
        float mean = s * (1.f / 768.f);
        float s2 = 0.f;
#pragma unroll
        for (int i = 0; i < 12; ++i) { float d = v[i] - mean; s2 += d * d; }
#pragma unroll
        for (int off = 32; off >= 1; off >>= 1) s2 += __shfl_xor(s2, off);
        float rstd = 1.f / (sqrtf(s2 * (1.f / 767.f)) + 1e-6f);
        bf16* orow = hout + (size_t)row * DM;
#pragma unroll
        for (int i = 0; i < 12; ++i) {
            int c = lane + i * 64;
            orow[c] = f2b(lg[c] * (v[i] - mean) * rstd + lb[c]);
        }
        return;
    }
    // ---- transpose part (fp32->bf16, [K,N]->[N,K]) ----
    __shared__ float tile[32][33];
    const float* W; bf16* WT; int K, N, n0, k0;
    if (id < 2304) {            // Wq/Wk/Wv/Wo: 768x768, 24x24 blocks each
        int z = id / 576, r = id % 576;
        W  = (z == 0) ? Wq : (z == 1) ? Wk : (z == 2) ? Wv : Wo;
        WT = (z == 0) ? WqT : (z == 1) ? WkT : (z == 2) ? WvT : WoT;
        K = 768; N = 768; n0 = (r % 24) * 32; k0 = (r / 24) * 32;
    } else if (id < 4608) {     // W1: [768,3072] -> [3072,768]
        int r = id - 2304; W = W1; WT = W1T;
        K = 768; N = 3072; n0 = (r % 96) * 32; k0 = (r / 96) * 32;
    } else {                    // W2: [3072,768] -> [768,3072]
        int r = id - 4608; W = W2; WT = W2T;
        K = 3072; N = 768; n0 = (r % 24) * 32; k0 = (r / 24) * 32;
    }
    int tx = threadIdx.x & 31, ty = threadIdx.x >> 5;
#pragma unroll
    for (int r = ty; r < 32; r += 8)
        tile[r][tx] = W[(size_t)(k0 + r) * N + n0 + tx];
    __syncthreads();
#pragma unroll
    for (int r = ty; r < 32; r += 8)
        WT[(size_t)(n0 + r) * K + k0 + tx] = f2b(tile[tx][r]);
}

// ---------------- LayerNorm (unbiased var, eps on std) --------
__global__ __launch_bounds__(256) void ln_fwd(const float* __restrict__ x,
                                              const float* __restrict__ g,
                                              const float* __restrict__ be,
                                              bf16* __restrict__ out) {
    int wid = threadIdx.x >> 6, lane = threadIdx.x & 63;
    int row = blockIdx.x * 4 + wid;
    const float* xr = x + (size_t)row * DM;
    float v[12];
    float s = 0.f;
#pragma unroll
    for (int i = 0; i < 12; ++i) { v[i] = xr[lane + i * 64]; s += v[i]; }
#pragma unroll
    for (int off = 32; off >= 1; off >>= 1) s += __shfl_xor(s, off);
    float mean = s * (1.f / 768.f);
    float s2 = 0.f;
#pragma unroll
    for (int i = 0; i < 12; ++i) { float d = v[i] - mean; s2 += d * d; }
#pragma unroll
    for (int off = 32; off >= 1; off >>= 1) s2 += __shfl_xor(s2, off);
    float rstd = 1.f / (sqrtf(s2 * (1.f / 767.f)) + 1e-6f);
    bf16* orow = out + (size_t)row * DM;
#pragma unroll
    for (int i = 0; i < 12; ++i) {
        int c = lane + i * 64;
        orow[c] = f2b(g[c] * (v[i] - mean) * rstd + be[c]);
    }
}

// ---------------- 128x128 GEMM core, BK=32, dbuf, prefetch-after-barrier -----
__device__ __forceinline__ void gemm_core(const bf16* __restrict__ A,
                                          const bf16* __restrict__ BT,
                                          int K, int bm, int bn,
                                          bf16* As, bf16* Bs,   // each 2*128*32
                                          f32x4 acc[4][4]) {
    int tid = threadIdx.x;
    int lane = tid & 63, quad = lane >> 4, lid = lane & 15;
    int wid = tid >> 6;
    int wm = (wid >> 1) * 64, wn = (wid & 1) * 64;
    int s0 = tid, s1 = tid + 256;
    int r0 = s0 >> 2, c0 = (s0 & 3) ^ ((r0 >> 1) & 3);
    int r1 = s1 >> 2, c1 = (s1 & 3) ^ ((r1 >> 1) & 3);
    const bf16* A0 = A + (size_t)(bm + r0) * K + c0 * 8;
    const bf16* A1 = A + (size_t)(bm + r1) * K + c1 * 8;
    const bf16* B0 = BT + (size_t)(bn + r0) * K + c0 * 8;
    const bf16* B1 = BT + (size_t)(bn + r1) * K + c1 * 8;
    int rdc = quad ^ ((lid >> 1) & 3);
    g2l16(A0, As + s0 * 8);
    g2l16(B0, Bs + s0 * 8);
    g2l16(A1, As + s1 * 8);
    g2l16(B1, Bs + s1 * 8);
    for (int k0 = 0; k0 < K; k0 += 32) {
        __syncthreads();
        int cur = (k0 >> 5) & 1;
        if (k0 + 32 < K) {
            int nb = (cur ^ 1) * 4096;
            g2l16(A0 + k0 + 32, As + nb + s0 * 8);
            g2l16(B0 + k0 + 32, Bs + nb + s0 * 8);
            g2l16(A1 + k0 + 32, As + nb + s1 * 8);
            g2l16(B1 + k0 + 32, Bs + nb + s1 * 8);
        }
        const bf16* Ac = As + cur * 4096;
        const bf16* Bc = Bs + cur * 4096;
        bf16x8 af[4], bfr[4];
#pragma unroll
        for (int i = 0; i < 4; ++i) af[i]  = *(const bf16x8*)&Ac[(wm + i * 16 + lid) * 32 + rdc * 8];
#pragma unroll
        for (int j = 0; j < 4; ++j) bfr[j] = *(const bf16x8*)&Bc[(wn + j * 16 + lid) * 32 + rdc * 8];
#pragma unroll
        for (int i = 0; i < 4; ++i)
#pragma unroll
            for (int j = 0; j < 4; ++j)
                acc[i][j] = MFMA16(af[i], bfr[j], acc[i][j]);
    }
}

// ---------------- fused QKV projection, 128x96 tiles --------------------
// R7: retile 128x128(18x32=576 blocks, 2.25/CU imbalanced) -> 128x96 (768
// blocks = exactly 3/CU) + XCD swizzle. 96 | 768 so each block lies fully in
// one of Q/K/V; per wave 64x48 (af4+bfr3, 12 MFMA).
__global__ __launch_bounds__(256) void gemm_qkv(const bf16* __restrict__ A,
                                                const bf16* __restrict__ WqT,
                                                const bf16* __restrict__ WkT,
                                                const bf16* __restrict__ WvT,
                                                const float* __restrict__ bq,
                                                const float* __restrict__ bk,
                                                const float* __restrict__ bv,
                                                bf16* __restrict__ qb,
                                                bf16* __restrict__ kb,
                                                bf16* __restrict__ vtb) {
    __shared__ bf16 As[2 * 128 * 32];   // 16 KB
    __shared__ bf16 Bs[2 * 96 * 32];    // 12 KB
    int wg = xcd_swz(blockIdx.x, 768);
    int bnx = wg % 24;                  // global 96-col tile (0..23)
    int bm = (wg / 24) * 128;
    int which = bnx / 8;                // block-uniform
    int bn = (bnx % 8) * 96;            // col offset within the 768-wide output
    const bf16* BT = (which == 0) ? WqT : (which == 1) ? WkT : WvT;
    const float* bias = (which == 0) ? bq : (which == 1) ? bk : bv;

    int tid = threadIdx.x, wid = tid >> 6, lane = tid & 63, quad = lane >> 4, lid = lane & 15;
    int wm = (wid >> 1) * 64, wn = (wid & 1) * 48;
    f32x4 acc[4][3] = {};
    int s0 = tid, s1 = tid + 256;
    int r0 = s0 >> 2, c0 = (s0 & 3) ^ ((r0 >> 1) & 3);
    int r1 = s1 >> 2, c1 = (s1 & 3) ^ ((r1 >> 1) & 3);
    const bf16* A0 = A + (size_t)(bm + r0) * DM + c0 * 8;
    const bf16* A1 = A + (size_t)(bm + r1) * DM + c1 * 8;
    const bf16* B0 = BT + (size_t)(bn + r0) * DM + c0 * 8;
    const bf16* B1 = BT + (size_t)(bn + r1) * DM + c1 * 8;   // rows 64..95 (tid<128)
    int rdc = quad ^ ((lid >> 1) & 3);
    bool doB1 = tid < 128;              // wave-uniform
    g2l16(A0, As + s0 * 8);
    g2l16(A1, As + s1 * 8);
    g2l16(B0, Bs + s0 * 8);
    if (doB1) g2l16(B1, Bs + s1 * 8);
    for (int k0 = 0; k0 < DM; k0 += 32) {
        __syncthreads();
        int cur = (k0 >> 5) & 1;
        if (k0 + 32 < DM) {
            g2l16(A0 + k0 + 32, As + (cur ^ 1) * 4096 + s0 * 8);
            g2l16(A1 + k0 + 32, As + (cur ^ 1) * 4096 + s1 * 8);
            g2l16(B0 + k0 + 32, Bs + (cur ^ 1) * 3072 + s0 * 8);
            if (doB1) g2l16(B1 + k0 + 32, Bs + (cur ^ 1) * 3072 + s1 * 8);
        }
        const bf16* Ac = As + cur * 4096;
        const bf16* Bc = Bs + cur * 3072;
        bf16x8 af[4], bfr[3];
#pragma unroll
        for (int i = 0; i < 4; ++i) af[i]  = *(const bf16x8*)&Ac[(wm + i * 16 + lid) * 32 + rdc * 8];
#pragma unroll
        for (int j = 0; j < 3; ++j) bfr[j] = *(const bf16x8*)&Bc[(wn + j * 16 + lid) * 32 + rdc * 8];
#pragma unroll
        for (int i = 0; i < 4; ++i)
#pragma unroll
            for (int j = 0; j < 3; ++j)
                acc[i][j] = MFMA16(af[i], bfr[j], acc[i][j]);
    }

    float sc = (which == 0) ? QSCALE : 1.f;   // fold softmax scale+log2e into Q
#pragma unroll
    for (int j = 0; j < 3; ++j) {
        int col = bn + wn + j * 16 + lid;
        float bb = bias[col];
        int hh = col >> 6, d = col & 63;
#pragma unroll
        for (int i = 0; i < 4; ++i) {
            int rowbase = bm + wm + i * 16 + quad * 4;
            int b = rowbase >> 11;
            int s0r = rowbase & 2047;
            if (which == 2) {
                ushort4 pk;
                pk.x = f2b_bits(acc[i][j][0] + bb);
                pk.y = f2b_bits(acc[i][j][1] + bb);
                pk.z = f2b_bits(acc[i][j][2] + bb);
                pk.w = f2b_bits(acc[i][j][3] + bb);
                *(ushort4*)&vtb[(((size_t)b * NH + hh) * DK + d) * SS + s0r] = pk;
            } else {
                bf16* dst = which ? kb : qb;
#pragma unroll
                for (int r = 0; r < 4; ++r)
                    dst[(((size_t)b * NH + hh) * SS + (s0r + r)) * DK + d] = f2b((acc[i][j][r] + bb) * sc);
            }
        }
    }
}

// ---------------- 128x128 GEMM with epilogues (FFN1) ---------------
template <int EPI>
__global__ __launch_bounds__(256) void gemm_ep(const bf16* __restrict__ A,
                                               const bf16* __restrict__ BT,
                                               const float* __restrict__ bias,
                                               const float* __restrict__ res,
                                               void* __restrict__ outp,
                                               int N, int K) {
    __shared__ bf16 As[2 * 128 * 32];
    __shared__ bf16 Bs[2 * 128 * 32];
    int bm = blockIdx.y * 128, bn = blockIdx.x * 128;
    f32x4 acc[4][4] = {};
    gemm_core(A, BT, K, bm, bn, As, Bs, acc);

    int tid = threadIdx.x, wid = tid >> 6, lane = tid & 63, quad = lane >> 4, lid = lane & 15;
    int wm = (wid >> 1) * 64, wn = (wid & 1) * 64;
#pragma unroll
    for (int j = 0; j < 4; ++j) {
        int col = bn + wn + j * 16 + lid;
        float bb = bias[col];
#pragma unroll
        for (int i = 0; i < 4; ++i) {
#pragma unroll
            for (int r = 0; r < 4; ++r) {
                int row = bm + wm + i * 16 + quad * 4 + r;
                float v = acc[i][j][r] + bb;
                if (EPI == 2) {
                    ((float*)outp)[(size_t)row * N + col] = res[(size_t)row * N + col] + v;
                } else {
                    ((bf16*)outp)[(size_t)row * N + col] = f2b(fmaxf(v, 0.f));
                }
            }
        }
    }
}

// ---------------- 64x128 GEMM, in-block split-K (FFN2) ----------------------
// R4-proven best for FFN2 (47.9 us vs ep96's 54.5). 512 threads: half h owns
// K-range [h*K/2,(h+1)*K/2) with its own As/Bs dbuf; barriers align across
// halves. R7 adds the XCD-chunk swizzle: consecutive bids share bm but were
// round-robined across 8 XCDs -> each per-XCD L2 re-fetched the same A panel
// (FETCH 107 MB vs ~41 ideal). Chunked wg gives each XCD a contiguous bm
// range (A chunk ~3 MB < 4 MB L2).
template <int EPI>
__global__ __launch_bounds__(512) void gemm_ep64(const bf16* __restrict__ A,
                                                 const bf16* __restrict__ BT,
                                                 const float* __restrict__ bias,
                                                 const float* __restrict__ res,
                                                 void* __restrict__ outp,
                                                 int N, int K) {
    __shared__ char smem[49152];   // 16KB As (2 halves) + 32KB Bs (2 halves)
    int tid = threadIdx.x;
    int half = tid >> 8, htid = tid & 255;
    bf16* As = (bf16*)smem + half * 4096;            // per-half: 2 bufs x 64x32
    bf16* Bs = (bf16*)(smem + 16384) + half * 8192;  // per-half: 2 bufs x 128x32
    int K2 = K >> 1, koff = half * K2;
    int wg = xcd_swz(blockIdx.x, gridDim.x);
    int bm = (wg / 6) * 64, bn = (wg % 6) * 128;
    int wid = htid >> 6, lane = tid & 63, quad = lane >> 4, lid = lane & 15;
    int wm = (wid >> 1) * 32, wn = (wid & 1) * 64;
    f32x4 acc[2][4] = {};
    int ra = htid >> 2, ca = (htid & 3) ^ ((ra >> 1) & 3);
    int s0 = htid, s1 = htid + 256;
    int rb0 = s0 >> 2, cb0 = (s0 & 3) ^ ((rb0 >> 1) & 3);
    int rb1 = s1 >> 2, cb1 = (s1 & 3) ^ ((rb1 >> 1) & 3);
    const bf16* Ap = A + (size_t)(bm + ra) * K + koff + ca * 8;
    const bf16* B0 = BT + (size_t)(bn + rb0) * K + koff + cb0 * 8;
    const bf16* B1 = BT + (size_t)(bn + rb1) * K + koff + cb1 * 8;
    int rdc = quad ^ ((lid >> 1) & 3);
    g2l16(Ap, As + htid * 8);
    g2l16(B0, Bs + s0 * 8);
    g2l16(B1, Bs + s1 * 8);
    for (int k0 = 0; k0 < K2; k0 += 32) {
        __syncthreads();
        int cur = (k0 >> 5) & 1;
        if (k0 + 32 < K2) {
            g2l16(Ap + k0 + 32, As + (cur ^ 1) * 2048 + htid * 8);
            g2l16(B0 + k0 + 32, Bs + (cur ^ 1) * 4096 + s0 * 8);
            g2l16(B1 + k0 + 32, Bs + (cur ^ 1) * 4096 + s1 * 8);
        }
        const bf16* Ac = As + cur * 2048;
        const bf16* Bc = Bs + cur * 4096;
        bf16x8 af[2], bfr[4];
#pragma unroll
        for (int i = 0; i < 2; ++i) af[i]  = *(const bf16x8*)&Ac[(wm + i * 16 + lid) * 32 + rdc * 8];
#pragma unroll
        for (int j = 0; j < 4; ++j) bfr[j] = *(const bf16x8*)&Bc[(wn + j * 16 + lid) * 32 + rdc * 8];
#pragma unroll
        for (int i = 0; i < 2; ++i)
#pragma unroll
            for (int j = 0; j < 4; ++j)
                acc[i][j] = MFMA16(af[i], bfr[j], acc[i][j]);
    }
    // ---- cross-half reduction through LDS (reuses As/Bs region) ----
    __syncthreads();               // all As/Bs reads complete block-wide
    float* red = (float*)smem;     // 256 threads x 32 floats = 32KB
    if (half == 1) {
#pragma unroll
        for (int i = 0; i < 2; ++i)
#pragma unroll
            for (int j = 0; j < 4; ++j) {
                int c = i * 4 + j;
                *(f32x4*)&red[htid * 32 + ((c ^ (htid & 7)) << 2)] = acc[i][j];
            }
    }
    __syncthreads();
    if (half == 0) {
#pragma unroll
        for (int i = 0; i < 2; ++i)
#pragma unroll
            for (int j = 0; j < 4; ++j) {
                int c = i * 4 + j;
                f32x4 o = *(const f32x4*)&red[htid * 32 + ((c ^ (htid & 7)) << 2)];
                acc[i][j] += o;
            }
#pragma unroll
        for (int j = 0; j < 4; ++j) {
            int col = bn + wn + j * 16 + lid;
            float bb = bias[col];
#pragma unroll
            for (int i = 0; i < 2; ++i) {
#pragma unroll
                for (int r = 0; r < 4; ++r) {
                    int row = bm + wm + i * 16 + quad * 4 + r;
                    float v = acc[i][j][r] + bb;
                    if (EPI == 2) {
                        ((float*)outp)[(size_t)row * N + col] = res[(size_t)row * N + col] + v;
                    } else {
                        ((bf16*)outp)[(size_t)row * N + col] = f2b(fmaxf(v, 0.f));
                    }
                }
            }
        }
    }
}

// ---------------- 64x96 GEMM (Wo projection), balanced grid -----------------
// Kept from R6 for Wo only (K=768); R7 adds XCD swizzle (grid 512, chunk 64).
template <int EPI>
__global__ __launch_bounds__(256) void gemm_ep96(const bf16* __restrict__ A,
                                                 const bf16* __restrict__ BT,
                                                 const float* __restrict__ bias,
                                                 const float* __restrict__ res,
                                                 void* __restrict__ outp,
                                                 int N, int K) {
    __shared__ bf16 As[2 * 64 * 32];    // 8 KB
    __shared__ bf16 Bs[2 * 96 * 32];    // 12 KB
    int wg = xcd_swz(blockIdx.x, gridDim.x);
    int bm = (wg / 8) * 64, bn = (wg % 8) * 96;
    int tid = threadIdx.x, wid = tid >> 6, lane = tid & 63, quad = lane >> 4, lid = lane & 15;
    int wm = (wid >> 1) * 32, wn = (wid & 1) * 48;
    f32x4 acc[2][3] = {};
    int ra = tid >> 2, ca = (tid & 3) ^ ((ra >> 1) & 3);
    int s0 = tid, s1 = tid + 256;            // B slots; s1 valid for tid<128 (rows 64..95)
    int rb0 = s0 >> 2, cb0 = (s0 & 3) ^ ((rb0 >> 1) & 3);
    int rb1 = s1 >> 2, cb1 = (s1 & 3) ^ ((rb1 >> 1) & 3);
    const bf16* Ap = A + (size_t)(bm + ra) * K + ca * 8;
    const bf16* B0 = BT + (size_t)(bn + rb0) * K + cb0 * 8;
    const bf16* B1 = BT + (size_t)(bn + rb1) * K + cb1 * 8;
    int rdc = quad ^ ((lid >> 1) & 3);
    bool doB1 = tid < 128;                   // wave-uniform (waves 0,1)
    g2l16(Ap, As + tid * 8);
    g2l16(B0, Bs + s0 * 8);
    if (doB1) g2l16(B1, Bs + s1 * 8);
    for (int k0 = 0; k0 < K; k0 += 32) {
        __syncthreads();
        int cur = (k0 >> 5) & 1;
        if (k0 + 32 < K) {
            g2l16(Ap + k0 + 32, As + (cur ^ 1) * 2048 + tid * 8);
            g2l16(B0 + k0 + 32, Bs + (cur ^ 1) * 3072 + s0 * 8);
            if (doB1) g2l16(B1 + k0 + 32, Bs + (cur ^ 1) * 3072 + s1 * 8);
        }
        const bf16* Ac = As + cur * 2048;
        const bf16* Bc = Bs + cur * 3072;
        bf16x8 af[2], bfr[3];
#pragma unroll
        for (int i = 0; i < 2; ++i) af[i]  = *(const bf16x8*)&Ac[(wm + i * 16 + lid) * 32 + rdc * 8];
#pragma unroll
        for (int j = 0; j < 3; ++j) bfr[j] = *(const bf16x8*)&Bc[(wn + j * 16 + lid) * 32 + rdc * 8];
#pragma unroll
        for (int i = 0; i < 2; ++i)
#pragma unroll
            for (int j = 0; j < 3; ++j)
                acc[i][j] = MFMA16(af[i], bfr[j], acc[i][j]);
    }
#pragma unroll
    for (int j = 0; j < 3; ++j) {
        int col = bn + wn + j * 16 + lid;
        float bb = bias[col];
#pragma unroll
        for (int i = 0; i < 2; ++i) {
#pragma unroll
            for (int r = 0; r < 4; ++r) {
                int row = bm + wm + i * 16 + quad * 4 + r;
                float v = acc[i][j][r] + bb;
                if (EPI == 2) {
                    ((float*)outp)[(size_t)row * N + col] = res[(size_t)row * N + col] + v;
                } else {
                    ((bf16*)outp)[(size_t)row * N + col] = f2b(fmaxf(v, 0.f));
                }
            }
        }
    }
}

// ---------------- flash attention, k-chunk partials (KCH=2) -----------------
// R3: QB=128, two 16-row q-strips per wave (kf/vf/mask reused across strips).
// R6: block-uniform mask fast-path. grid (SS/128, 24, KCH) = 768 blocks.
__global__ __launch_bounds__(256) void attn_part(const bf16* __restrict__ qb,
                                                 const bf16* __restrict__ kb,
                                                 const bf16* __restrict__ vtb,
                                                 const int* __restrict__ mask,
                                                 bf16* __restrict__ part,
                                                 float* __restrict__ lws) {
    __shared__ bf16 Ks[2 * 64 * 64];
    __shared__ bf16 VTs[2 * 64 * 64];
    __shared__ bf16 Ps[128 * 72];   // [q][k], stride 72 -> b128 reads benign
    int bh = blockIdx.y;
    int b = bh / NH;
    int q0 = blockIdx.x * 128;
    int kc = blockIdx.z;
    const bf16* Kp = kb  + (size_t)bh * SS * DK;
    const bf16* VT = vtb + (size_t)bh * DK * SS;
    int tid = threadIdx.x, wid = tid >> 6, lane = tid & 63, quad = lane >> 4, lid = lane & 15;

    int s0 = tid, s1 = tid + 256;
    int r0 = s0 >> 3, c0 = (s0 & 7) ^ (r0 & 7);
    int r1 = s1 >> 3, c1 = (s1 & 7) ^ (r1 & 7);

    const int* mrow = mask + b * SS;
    int tbeg = kc * (SS / 64 / KCH), tend = (kc + 1) * (SS / 64 / KCH);

    // block-uniform mask check over this block's k-range (1024 ints = 256xint4)
    int myfull;
    {
        const int4* m4 = (const int4*)(mrow + tbeg * 64);
        int4 mm = m4[tid];
        myfull = (mm.x != 0) & (mm.y != 0) & (mm.z != 0) & (mm.w != 0);
    }
    int blockfull = __syncthreads_and(myfull);

    // Q fragments for both strips; same lane mapping serves as B-operand for S^T
    bf16x8 qf0[2], qf1[2];
#pragma unroll
    for (int u = 0; u < 2; ++u) {
        const bf16* Qrow = qb + ((size_t)bh * SS + q0 + wid * 32 + u * 16 + lid) * DK;
        qf0[u] = *(const bf16x8*)&Qrow[quad * 8];
        qf1[u] = *(const bf16x8*)&Qrow[32 + quad * 8];
    }

    bf16x8 ones;
#pragma unroll
    for (int i = 0; i < 8; ++i) ones[i] = (short)0x3F80;   // bf16 1.0

    int rdc  = quad ^ (lid & 7);
    int rdc2 = rdc ^ 4;

    f32x4 accv[2][4] = {};
    f32x4 accl[2] = {};

    // prologue: stage tile tbeg into buffer 0
    {
        int k0 = tbeg * 64;
        g2l16(Kp + (size_t)(k0 + r0) * DK + c0 * 8, Ks + s0 * 8);
        g2l16(Kp + (size_t)(k0 + r1) * DK + c1 * 8, Ks + s1 * 8);
        g2l16(VT + (size_t)r0 * SS + k0 + c0 * 8, VTs + s0 * 8);
        g2l16(VT + (size_t)r1 * SS + k0 + c1 * 8, VTs + s1 * 8);
    }

    int cur = 0;
    for (int t = tbeg; t < tend; ++t) {
        int k0 = t * 64;
        __syncthreads();   // buf[cur] staged (vmcnt drained); prev tile's reads done
        if (t + 1 < tend) {   // prefetch t+1 into alternate buffer
            int k0n = (t + 1) * 64;
            int nb = (cur ^ 1) * 4096;
            g2l16(Kp + (size_t)(k0n + r0) * DK + c0 * 8, Ks + nb + s0 * 8);
            g2l16(Kp + (size_t)(k0n + r1) * DK + c1 * 8, Ks + nb + s1 * 8);
            g2l16(VT + (size_t)r0 * SS + k0n + c0 * 8, VTs + nb + s0 * 8);
            g2l16(VT + (size_t)r1 * SS + k0n + c1 * 8, VTs + nb + s1 * 8);
        }
        const bf16* Kc  = Ks  + cur * 4096;
        const bf16* VTc = VTs + cur * 4096;

        // S^T: lane holds k = ns*16 + quad*4 + r, q = (strip base) + lid.
#pragma unroll
        for (int ns = 0; ns < 4; ++ns) {
            bf16x8 kf0 = *(const bf16x8*)&Kc[(ns * 16 + lid) * 64 + rdc * 8];
            bf16x8 kf1 = *(const bf16x8*)&Kc[(ns * 16 + lid) * 64 + rdc2 * 8];
#pragma unroll
            for (int u = 0; u < 2; ++u) {
                f32x4 st = {};
                st = MFMA16(kf0, qf0[u], st);
                st = MFMA16(kf1, qf1[u], st);
                float p0, p1, p2, p3;
                if (blockfull) {
                    p0 = EXP2F(st[0]);
                    p1 = EXP2F(st[1]);
                    p2 = EXP2F(st[2]);
                    p3 = EXP2F(st[3]);
                } else {
                    int4 mk = *(const int4*)&mrow[k0 + ns * 16 + quad * 4];
                    p0 = mk.x ? EXP2F(st[0]) : 0.f;
                    p1 = mk.y ? EXP2F(st[1]) : 0.f;
                    p2 = mk.z ? EXP2F(st[2]) : 0.f;
                    p3 = mk.w ? EXP2F(st[3]) : 0.f;
                }
                __hip_bfloat162 h01 = __float22bfloat162_rn(make_float2(p0, p1));
                __hip_bfloat162 h23 = __float22bfloat162_rn(make_float2(p2, p3));
                uint2 pw;
                pw.x = *(unsigned int*)&h01;
                pw.y = *(unsigned int*)&h23;
                *(uint2*)&Ps[(wid * 32 + u * 16 + lid) * 72 + ns * 16 + quad * 4] = pw;
            }
        }

        // P A-frags (same-wave round trip, no barrier)
        bf16x8 pa0[2], pa1[2];
#pragma unroll
        for (int u = 0; u < 2; ++u) {
            pa0[u] = *(const bf16x8*)&Ps[(wid * 32 + u * 16 + lid) * 72 + quad * 8];
            pa1[u] = *(const bf16x8*)&Ps[(wid * 32 + u * 16 + lid) * 72 + 32 + quad * 8];
            accl[u] = MFMA16(pa0[u], ones, accl[u]);
            accl[u] = MFMA16(pa1[u], ones, accl[u]);
        }

        // PV: vf fragments loaded once, reused for both strips
#pragma unroll
        for (int ds = 0; ds < 4; ++ds) {
            bf16x8 vf0 = *(const bf16x8*)&VTc[(ds * 16 + lid) * 64 + rdc * 8];
            bf16x8 vf1 = *(const bf16x8*)&VTc[(ds * 16 + lid) * 64 + rdc2 * 8];
#pragma unroll
            for (int u = 0; u < 2; ++u) {
                accv[u][ds] = MFMA16(pa0[u], vf0, accv[u][ds]);
                accv[u][ds] = MFMA16(pa1[u], vf1, accv[u][ds]);
            }
        }
        cur ^= 1;
    }

    bf16* pb = part + ((size_t)kc * (2 * NH) + bh) * DK * SS;
#pragma unroll
    for (int u = 0; u < 2; ++u) {
        if (lid == 0) {
#pragma unroll
            for (int r = 0; r < 4; ++r)
                lws[((size_t)kc * (2 * NH) + bh) * SS + q0 + wid * 32 + u * 16 + quad * 4 + r] = accl[u][r];
        }
        int qbase = q0 + wid * 32 + u * 16 + quad * 4;
#pragma unroll
        for (int ds = 0; ds < 4; ++ds) {
            int d = ds * 16 + lid;
            ushort4 pk;
            pk.x = f2b_bits(accv[u][ds][0]);
            pk.y = f2b_bits(accv[u][ds][1]);
            pk.z = f2b_bits(accv[u][ds][2]);
            pk.w = f2b_bits(accv[u][ds][3]);
            *(ushort4*)&pb[(size_t)d * SS + qbase] = pk;
        }
    }
}

// combine with LDS transpose: block per (64-q tile, bh).
__global__ __launch_bounds__(256) void attn_combine(const bf16* __restrict__ part,
                                                    const float* __restrict__ lws,
                                                    bf16* __restrict__ ctx) {
    __shared__ float tile[64][66];
    __shared__ float linv[64];
    int bh = blockIdx.y;
    int b = bh / NH, h = bh % NH;
    int q0 = blockIdx.x * 64;
    int tid = threadIdx.x;

    if (tid < 64) {
        float l = 0.f;
#pragma unroll
        for (int kc = 0; kc < KCH; ++kc)
            l += lws[((size_t)kc * (2 * NH) + bh) * SS + q0 + tid];
        linv[tid] = 1.f / l;
    }

    int d = tid >> 2, qs = (tid & 3) * 16;
    const bf16* p0 = part + (((size_t)0 * (2 * NH) + bh) * DK + d) * SS + q0 + qs;
    const bf16* p1 = part + (((size_t)1 * (2 * NH) + bh) * DK + d) * SS + q0 + qs;
    bf16x8 a0 = *(const bf16x8*)p0;
    bf16x8 a1 = *(const bf16x8*)(p0 + 8);
    bf16x8 b0 = *(const bf16x8*)p1;
    bf16x8 b1 = *(const bf16x8*)(p1 + 8);
#pragma unroll
    for (int i = 0; i < 8; ++i) {
        tile[d][qs + i]     = b2f(((const bf16*)&a0)[i]) + b2f(((const bf16*)&b0)[i]);
        tile[d][qs + 8 + i] = b2f(((const bf16*)&a1)[i]) + b2f(((const bf16*)&b1)[i]);
    }
    __syncthreads();

    int q = tid >> 2, ds2 = (tid & 3) * 16;
    float rl = linv[q];
    unsigned int wv[8];
#pragma unroll
    for (int i = 0; i < 8; ++i) {
        __hip_bfloat162 hh = __float22bfloat162_rn(
            make_float2(tile[ds2 + 2 * i][q] * rl, tile[ds2 + 2 * i + 1][q] * rl));
        wv[i] = *(unsigned int*)&hh;
    }
    bf16* crow = ctx + (size_t)(b * SS + q0 + q) * DM + h * DK + ds2;
    uint4 u0 = {wv[0], wv[1], wv[2], wv[3]};
    uint4 u1 = {wv[4], wv[5], wv[6], wv[7]};
    *(uint4*)&crow[0] = u0;
    *(uint4*)&crow[8] = u1;
}

// ---------------- host launch ----------------------------------------------
extern "C" void kernel_launch(void* const* d_in, const int* in_sizes, int n_in,
                              void* d_out, int out_size, void* d_ws, size_t ws_size,
                              hipStream_t stream) {
    const float* x    = (const float*)d_in[0];
    const int*   mask = (const int*)d_in[1];
    const float* Wq   = (const float*)d_in[2];
    const float* bq   = (const float*)d_in[3];
    const float* Wk   = (const float*)d_in[4];
    const float* bk   = (const float*)d_in[5];
    const float* Wv   = (const float*)d_in[6];
    const float* bv   = (const float*)d_in[7];
    const float* Wo   = (const float*)d_in[8];
    const float* bo   = (const float*)d_in[9];
    const float* ln1a = (const float*)d_in[10];
    const float* ln1b = (const float*)d_in[11];
    const float* W1   = (const float*)d_in[12];
    const float* b1   = (const float*)d_in[13];
    const float* W2   = (const float*)d_in[14];
    const float* b2   = (const float*)d_in[15];
    const float* ln2a = (const float*)d_in[16];
    const float* ln2b = (const float*)d_in[17];
    float* out = (float*)d_out;

    char* w = (char*)d_ws;
    bf16* h   = (bf16*)w; w += (size_t)NTOK * DM * 2;
    bf16* qb  = (bf16*)w; w += (size_t)NTOK * DM * 2;
    bf16* kb  = (bf16*)w; w += (size_t)NTOK * DM * 2;
    bf16* vtb = (bf16*)w; w += (size_t)NTOK * DM * 2;
    bf16* ctx = (bf16*)w; w += (size_t)NTOK * DM * 2;
    bf16* h2  = (bf16*)w; w += (size_t)NTOK * DM * 2;
    bf16* ffa = (bf16*)w; w += (size_t)NTOK * DFF * 2;   // also attn partials (temporally disjoint)
    float* x1 = (float*)w; w += (size_t)NTOK * DM * 4;   // also attn l-partials (temporally disjoint)
    bf16* WqT = (bf16*)w; w += (size_t)DM * DM * 2;
    bf16* WkT = (bf16*)w; w += (size_t)DM * DM * 2;
    bf16* WvT = (bf16*)w; w += (size_t)DM * DM * 2;
    bf16* WoT = (bf16*)w; w += (size_t)DM * DM * 2;
    bf16* W1T = (bf16*)w; w += (size_t)DM * DFF * 2;
    bf16* W2T = (bf16*)w; w += (size_t)DM * DFF * 2;

    bf16*  part = ffa;          // KCH*2*NH*DK*SS*2 = 12.6 MB <= NTOK*DFF*2 (24 MB)
    float* lws  = x1;           // KCH*24*SS*4 = 384 KB < NTOK*DM*4

    fused_pre<<<6912 + NTOK / 4, 256, 0, stream>>>(Wq, Wk, Wv, Wo, W1, W2,
                                                   WqT, WkT, WvT, WoT, W1T, W2T,
                                                   x, ln1a, ln1b, h);
    gemm_qkv<<<768, 256, 0, stream>>>(h, WqT, WkT, WvT, bq, bk, bv, qb, kb, vtb);
    attn_part<<<dim3(SS / 128, 2 * NH, KCH), 256, 0, stream>>>(qb, kb, vtb, mask, part, lws);
    attn_combine<<<dim3(SS / 64, 2 * NH), 256, 0, stream>>>(part, lws, ctx);
    gemm_ep96<2><<<512, 256, 0, stream>>>(ctx, WoT, bo, x, (void*)x1, DM, DM);
    ln_fwd<<<NTOK / 4, 256, 0, stream>>>(x1, ln2a, ln2b, h2);
    gemm_ep<3><<<dim3(24, 32), 256, 0, stream>>>(h2, W1T, b1, nullptr, (void*)ffa, DFF, DM);
    gemm_ep64<2><<<384, 512, 0, stream>>>(ffa, W2T, b2, x1, (void*)out, DM, DFF);
}

// Round 8
// 270.568 us; speedup vs baseline: 1.0822x; 1.0083x over previous
//
#include <hip/hip_runtime.h>
#include <hip/hip_bf16.h>
#include <stdint.h>

#define DM 768
#define DFF 3072
#define NH 12
#define DK 64
#define SS 2048
#define NTOK 4096   // B*S = 2*2048
#define KCH 2       // attention k-chunks: 16x24x2 = 768 blocks = exactly 3/CU

typedef __hip_bfloat16 bf16;
typedef short bf16x8 __attribute__((ext_vector_type(8)));
typedef float f32x4 __attribute__((ext_vector_type(4)));

#define MFMA16(a, b, c) __builtin_amdgcn_mfma_f32_16x16x32_bf16((a), (b), (c), 0, 0, 0)

// 0.125 (1/sqrt(Dk)) * log2(e), folded into the Q projection so attention uses exp2
#define QSCALE 0.18033688011112042f

#if __has_builtin(__builtin_amdgcn_exp2f)
#define EXP2F(x) __builtin_amdgcn_exp2f(x)   // raw v_exp_f32, no libm fixup
#else
#define EXP2F(x) exp2f(x)
#endif

static __device__ __forceinline__ bf16 f2b(float f) { return __float2bfloat16(f); }
static __device__ __forceinline__ unsigned short f2b_bits(float f) {
    bf16 h = __float2bfloat16(f);
    return *reinterpret_cast<unsigned short*>(&h);
}
static __device__ __forceinline__ float b2f(bf16 h) { return __bfloat162float(h); }

// async 16B global->LDS DMA. LDS dest must be wave-uniform base + lane*16.
static __device__ __forceinline__ void g2l16(const void* g, void* l) {
    __builtin_amdgcn_global_load_lds(
        (const __attribute__((address_space(1))) unsigned int*)g,
        (__attribute__((address_space(3))) unsigned int*)(uintptr_t)l,
        16, 0, 0);
}

// bijective XCD-chunk swizzle (T1): grid must be a multiple of 8.
// round-robin dispatch (bid%8 = XCD) -> each XCD sees a CONTIGUOUS wg chunk.
static __device__ __forceinline__ int xcd_swz(int bid, int nwg) {
    int q = nwg >> 3;
    return (bid & 7) * q + (bid >> 3);
}

// ---- fused: 6 weight transposes (blocks 0..6911) + LayerNorm1 (6912..7935) --
__global__ __launch_bounds__(256) void fused_pre(const float* Wq, const float* Wk,
                                                 const float* Wv, const float* Wo,
                                                 const float* W1, const float* W2,
                                                 bf16* WqT, bf16* WkT, bf16* WvT,
                                                 bf16* WoT, bf16* W1T, bf16* W2T,
                                                 const float* __restrict__ x,
                                                 const float* __restrict__ lg,
                                                 const float* __restrict__ lb,
                                                 bf16* __restrict__ hout) {
    int id = blockIdx.x;
    if (id >= 6912) {
        // ---- LayerNorm part (1024 blocks x 4 rows) ----
        int wid = threadIdx.x >> 6, lane = threadIdx.x & 63;
        int row = (id - 6912) * 4 + wid;
        const float* xr = x + (size_t)row * DM;
        float v[12];
        float s = 0.f;
#pragma unroll
        for (int i = 0; i < 12; ++i) { v[i] = xr[lane + i * 64]; s += v[i]; }
#pragma unroll
        for (int off = 32; off >= 1; off >>= 1) s += __shfl_xor(s, off);
        float mean = s * (1.f / 768.f);
        float s2 = 0.f;
#pragma unroll
        for (int i = 0; i < 12; ++i) { float d = v[i] - mean; s2 += d * d; }
#pragma unroll
        for (int off = 32; off >= 1; off >>= 1) s2 += __shfl_xor(s2, off);
        float rstd = 1.f / (sqrtf(s2 * (1.f / 767.f)) + 1e-6f);
        bf16* orow = hout + (size_t)row * DM;
#pragma unroll
        for (int i = 0; i < 12; ++i) {
            int c = lane + i * 64;
            orow[c] = f2b(lg[c] * (v[i] - mean) * rstd + lb[c]);
        }
        return;
    }
    // ---- transpose part (fp32->bf16, [K,N]->[N,K]) ----
    __shared__ float tile[32][33];
    const float* W; bf16* WT; int K, N, n0, k0;
    if (id < 2304) {            // Wq/Wk/Wv/Wo: 768x768, 24x24 blocks each
        int z = id / 576, r = id % 576;
        W  = (z == 0) ? Wq : (z == 1) ? Wk : (z == 2) ? Wv : Wo;
        WT = (z == 0) ? WqT : (z == 1) ? WkT : (z == 2) ? WvT : WoT;
        K = 768; N = 768; n0 = (r % 24) * 32; k0 = (r / 24) * 32;
    } else if (id < 4608) {     // W1: [768,3072] -> [3072,768]
        int r = id - 2304; W = W1; WT = W1T;
        K = 768; N = 3072; n0 = (r % 96) * 32; k0 = (r / 96) * 32;
    } else {                    // W2: [3072,768] -> [768,3072]
        int r = id - 4608; W = W2; WT = W2T;
        K = 3072; N = 768; n0 = (r % 24) * 32; k0 = (r / 24) * 32;
    }
    int tx = threadIdx.x & 31, ty = threadIdx.x >> 5;
#pragma unroll
    for (int r = ty; r < 32; r += 8)
        tile[r][tx] = W[(size_t)(k0 + r) * N + n0 + tx];
    __syncthreads();
#pragma unroll
    for (int r = ty; r < 32; r += 8)
        WT[(size_t)(n0 + r) * K + k0 + tx] = f2b(tile[tx][r]);
}

// ---------------- LayerNorm (unbiased var, eps on std) --------
__global__ __launch_bounds__(256) void ln_fwd(const float* __restrict__ x,
                                              const float* __restrict__ g,
                                              const float* __restrict__ be,
                                              bf16* __restrict__ out) {
    int wid = threadIdx.x >> 6, lane = threadIdx.x & 63;
    int row = blockIdx.x * 4 + wid;
    const float* xr = x + (size_t)row * DM;
    float v[12];
    float s = 0.f;
#pragma unroll
    for (int i = 0; i < 12; ++i) { v[i] = xr[lane + i * 64]; s += v[i]; }
#pragma unroll
    for (int off = 32; off >= 1; off >>= 1) s += __shfl_xor(s, off);
    float mean = s * (1.f / 768.f);
    float s2 = 0.f;
#pragma unroll
    for (int i = 0; i < 12; ++i) { float d = v[i] - mean; s2 += d * d; }
#pragma unroll
    for (int off = 32; off >= 1; off >>= 1) s2 += __shfl_xor(s2, off);
    float rstd = 1.f / (sqrtf(s2 * (1.f / 767.f)) + 1e-6f);
    bf16* orow = out + (size_t)row * DM;
#pragma unroll
    for (int i = 0; i < 12; ++i) {
        int c = lane + i * 64;
        orow[c] = f2b(g[c] * (v[i] - mean) * rstd + be[c]);
    }
}

// ---------------- 128x128 GEMM core, BK=32, dbuf, prefetch-after-barrier -----
__device__ __forceinline__ void gemm_core(const bf16* __restrict__ A,
                                          const bf16* __restrict__ BT,
                                          int K, int bm, int bn,
                                          bf16* As, bf16* Bs,   // each 2*128*32
                                          f32x4 acc[4][4]) {
    int tid = threadIdx.x;
    int lane = tid & 63, quad = lane >> 4, lid = lane & 15;
    int wid = tid >> 6;
    int wm = (wid >> 1) * 64, wn = (wid & 1) * 64;
    int s0 = tid, s1 = tid + 256;
    int r0 = s0 >> 2, c0 = (s0 & 3) ^ ((r0 >> 1) & 3);
    int r1 = s1 >> 2, c1 = (s1 & 3) ^ ((r1 >> 1) & 3);
    const bf16* A0 = A + (size_t)(bm + r0) * K + c0 * 8;
    const bf16* A1 = A + (size_t)(bm + r1) * K + c1 * 8;
    const bf16* B0 = BT + (size_t)(bn + r0) * K + c0 * 8;
    const bf16* B1 = BT + (size_t)(bn + r1) * K + c1 * 8;
    int rdc = quad ^ ((lid >> 1) & 3);
    g2l16(A0, As + s0 * 8);
    g2l16(B0, Bs + s0 * 8);
    g2l16(A1, As + s1 * 8);
    g2l16(B1, Bs + s1 * 8);
    for (int k0 = 0; k0 < K; k0 += 32) {
        __syncthreads();
        int cur = (k0 >> 5) & 1;
        if (k0 + 32 < K) {
            int nb = (cur ^ 1) * 4096;
            g2l16(A0 + k0 + 32, As + nb + s0 * 8);
            g2l16(B0 + k0 + 32, Bs + nb + s0 * 8);
            g2l16(A1 + k0 + 32, As + nb + s1 * 8);
            g2l16(B1 + k0 + 32, Bs + nb + s1 * 8);
        }
        const bf16* Ac = As + cur * 4096;
        const bf16* Bc = Bs + cur * 4096;
        bf16x8 af[4], bfr[4];
#pragma unroll
        for (int i = 0; i < 4; ++i) af[i]  = *(const bf16x8*)&Ac[(wm + i * 16 + lid) * 32 + rdc * 8];
#pragma unroll
        for (int j = 0; j < 4; ++j) bfr[j] = *(const bf16x8*)&Bc[(wn + j * 16 + lid) * 32 + rdc * 8];
#pragma unroll
        for (int i = 0; i < 4; ++i)
#pragma unroll
            for (int j = 0; j < 4; ++j)
                acc[i][j] = MFMA16(af[i], bfr[j], acc[i][j]);
    }
}

// ---------------- fused QKV projection, 128x96 tiles --------------------
// R7: 768 blocks = exactly 3/CU + XCD swizzle; per wave 64x48.
__global__ __launch_bounds__(256) void gemm_qkv(const bf16* __restrict__ A,
                                                const bf16* __restrict__ WqT,
                                                const bf16* __restrict__ WkT,
                                                const bf16* __restrict__ WvT,
                                                const float* __restrict__ bq,
                                                const float* __restrict__ bk,
                                                const float* __restrict__ bv,
                                                bf16* __restrict__ qb,
                                                bf16* __restrict__ kb,
                                                bf16* __restrict__ vtb) {
    __shared__ bf16 As[2 * 128 * 32];   // 16 KB
    __shared__ bf16 Bs[2 * 96 * 32];    // 12 KB
    int wg = xcd_swz(blockIdx.x, 768);
    int bnx = wg % 24;                  // global 96-col tile (0..23)
    int bm = (wg / 24) * 128;
    int which = bnx / 8;                // block-uniform
    int bn = (bnx % 8) * 96;            // col offset within the 768-wide output
    const bf16* BT = (which == 0) ? WqT : (which == 1) ? WkT : WvT;
    const float* bias = (which == 0) ? bq : (which == 1) ? bk : bv;

    int tid = threadIdx.x, wid = tid >> 6, lane = tid & 63, quad = lane >> 4, lid = lane & 15;
    int wm = (wid >> 1) * 64, wn = (wid & 1) * 48;
    f32x4 acc[4][3] = {};
    int s0 = tid, s1 = tid + 256;
    int r0 = s0 >> 2, c0 = (s0 & 3) ^ ((r0 >> 1) & 3);
    int r1 = s1 >> 2, c1 = (s1 & 3) ^ ((r1 >> 1) & 3);
    const bf16* A0 = A + (size_t)(bm + r0) * DM + c0 * 8;
    const bf16* A1 = A + (size_t)(bm + r1) * DM + c1 * 8;
    const bf16* B0 = BT + (size_t)(bn + r0) * DM + c0 * 8;
    const bf16* B1 = BT + (size_t)(bn + r1) * DM + c1 * 8;   // rows 64..95 (tid<128)
    int rdc = quad ^ ((lid >> 1) & 3);
    bool doB1 = tid < 128;              // wave-uniform
    g2l16(A0, As + s0 * 8);
    g2l16(A1, As + s1 * 8);
    g2l16(B0, Bs + s0 * 8);
    if (doB1) g2l16(B1, Bs + s1 * 8);
    for (int k0 = 0; k0 < DM; k0 += 32) {
        __syncthreads();
        int cur = (k0 >> 5) & 1;
        if (k0 + 32 < DM) {
            g2l16(A0 + k0 + 32, As + (cur ^ 1) * 4096 + s0 * 8);
            g2l16(A1 + k0 + 32, As + (cur ^ 1) * 4096 + s1 * 8);
            g2l16(B0 + k0 + 32, Bs + (cur ^ 1) * 3072 + s0 * 8);
            if (doB1) g2l16(B1 + k0 + 32, Bs + (cur ^ 1) * 3072 + s1 * 8);
        }
        const bf16* Ac = As + cur * 4096;
        const bf16* Bc = Bs + cur * 3072;
        bf16x8 af[4], bfr[3];
#pragma unroll
        for (int i = 0; i < 4; ++i) af[i]  = *(const bf16x8*)&Ac[(wm + i * 16 + lid) * 32 + rdc * 8];
#pragma unroll
        for (int j = 0; j < 3; ++j) bfr[j] = *(const bf16x8*)&Bc[(wn + j * 16 + lid) * 32 + rdc * 8];
#pragma unroll
        for (int i = 0; i < 4; ++i)
#pragma unroll
            for (int j = 0; j < 3; ++j)
                acc[i][j] = MFMA16(af[i], bfr[j], acc[i][j]);
    }

    float sc = (which == 0) ? QSCALE : 1.f;   // fold softmax scale+log2e into Q
#pragma unroll
    for (int j = 0; j < 3; ++j) {
        int col = bn + wn + j * 16 + lid;
        float bb = bias[col];
        int hh = col >> 6, d = col & 63;
#pragma unroll
        for (int i = 0; i < 4; ++i) {
            int rowbase = bm + wm + i * 16 + quad * 4;
            int b = rowbase >> 11;
            int s0r = rowbase & 2047;
            if (which == 2) {
                ushort4 pk;
                pk.x = f2b_bits(acc[i][j][0] + bb);
                pk.y = f2b_bits(acc[i][j][1] + bb);
                pk.z = f2b_bits(acc[i][j][2] + bb);
                pk.w = f2b_bits(acc[i][j][3] + bb);
                *(ushort4*)&vtb[(((size_t)b * NH + hh) * DK + d) * SS + s0r] = pk;
            } else {
                bf16* dst = which ? kb : qb;
#pragma unroll
                for (int r = 0; r < 4; ++r)
                    dst[(((size_t)b * NH + hh) * SS + (s0r + r)) * DK + d] = f2b((acc[i][j][r] + bb) * sc);
            }
        }
    }
}

// ---------------- 128x128 GEMM with epilogues (FFN1) ---------------
// R8: XCD-chunk swizzle (the last GEMM still missing it). Linear grid 768
// (mult of 8), bm-major chunks: each XCD gets 4 bm-rows x 24 bn-cols ->
// per-XCD working set A 0.8MB + B 4.7MB (vs unswizzled cross-XCD re-fetch).
template <int EPI>
__global__ __launch_bounds__(256) void gemm_ep(const bf16* __restrict__ A,
                                               const bf16* __restrict__ BT,
                                               const float* __restrict__ bias,
                                               const float* __restrict__ res,
                                               void* __restrict__ outp,
                                               int N, int K) {
    __shared__ bf16 As[2 * 128 * 32];
    __shared__ bf16 Bs[2 * 128 * 32];
    int wg = xcd_swz(blockIdx.x, gridDim.x);
    int bm = (wg / 24) * 128, bn = (wg % 24) * 128;
    f32x4 acc[4][4] = {};
    gemm_core(A, BT, K, bm, bn, As, Bs, acc);

    int tid = threadIdx.x, wid = tid >> 6, lane = tid & 63, quad = lane >> 4, lid = lane & 15;
    int wm = (wid >> 1) * 64, wn = (wid & 1) * 64;
#pragma unroll
    for (int j = 0; j < 4; ++j) {
        int col = bn + wn + j * 16 + lid;
        float bb = bias[col];
#pragma unroll
        for (int i = 0; i < 4; ++i) {
#pragma unroll
            for (int r = 0; r < 4; ++r) {
                int row = bm + wm + i * 16 + quad * 4 + r;
                float v = acc[i][j][r] + bb;
                if (EPI == 2) {
                    ((float*)outp)[(size_t)row * N + col] = res[(size_t)row * N + col] + v;
                } else {
                    ((bf16*)outp)[(size_t)row * N + col] = f2b(fmaxf(v, 0.f));
                }
            }
        }
    }
}

// ---------------- 64x128 GEMM, in-block split-K (FFN2) ----------------------
// R4-proven best for FFN2 + R7 XCD swizzle.
template <int EPI>
__global__ __launch_bounds__(512) void gemm_ep64(const bf16* __restrict__ A,
                                                 const bf16* __restrict__ BT,
                                                 const float* __restrict__ bias,
                                                 const float* __restrict__ res,
                                                 void* __restrict__ outp,
                                                 int N, int K) {
    __shared__ char smem[49152];   // 16KB As (2 halves) + 32KB Bs (2 halves)
    int tid = threadIdx.x;
    int half = tid >> 8, htid = tid & 255;
    bf16* As = (bf16*)smem + half * 4096;            // per-half: 2 bufs x 64x32
    bf16* Bs = (bf16*)(smem + 16384) + half * 8192;  // per-half: 2 bufs x 128x32
    int K2 = K >> 1, koff = half * K2;
    int wg = xcd_swz(blockIdx.x, gridDim.x);
    int bm = (wg / 6) * 64, bn = (wg % 6) * 128;
    int wid = htid >> 6, lane = tid & 63, quad = lane >> 4, lid = lane & 15;
    int wm = (wid >> 1) * 32, wn = (wid & 1) * 64;
    f32x4 acc[2][4] = {};
    int ra = htid >> 2, ca = (htid & 3) ^ ((ra >> 1) & 3);
    int s0 = htid, s1 = htid + 256;
    int rb0 = s0 >> 2, cb0 = (s0 & 3) ^ ((rb0 >> 1) & 3);
    int rb1 = s1 >> 2, cb1 = (s1 & 3) ^ ((rb1 >> 1) & 3);
    const bf16* Ap = A + (size_t)(bm + ra) * K + koff + ca * 8;
    const bf16* B0 = BT + (size_t)(bn + rb0) * K + koff + cb0 * 8;
    const bf16* B1 = BT + (size_t)(bn + rb1) * K + koff + cb1 * 8;
    int rdc = quad ^ ((lid >> 1) & 3);
    g2l16(Ap, As + htid * 8);
    g2l16(B0, Bs + s0 * 8);
    g2l16(B1, Bs + s1 * 8);
    for (int k0 = 0; k0 < K2; k0 += 32) {
        __syncthreads();
        int cur = (k0 >> 5) & 1;
        if (k0 + 32 < K2) {
            g2l16(Ap + k0 + 32, As + (cur ^ 1) * 2048 + htid * 8);
            g2l16(B0 + k0 + 32, Bs + (cur ^ 1) * 4096 + s0 * 8);
            g2l16(B1 + k0 + 32, Bs + (cur ^ 1) * 4096 + s1 * 8);
        }
        const bf16* Ac = As + cur * 2048;
        const bf16* Bc = Bs + cur * 4096;
        bf16x8 af[2], bfr[4];
#pragma unroll
        for (int i = 0; i < 2; ++i) af[i]  = *(const bf16x8*)&Ac[(wm + i * 16 + lid) * 32 + rdc * 8];
#pragma unroll
        for (int j = 0; j < 4; ++j) bfr[j] = *(const bf16x8*)&Bc[(wn + j * 16 + lid) * 32 + rdc * 8];
#pragma unroll
        for (int i = 0; i < 2; ++i)
#pragma unroll
            for (int j = 0; j < 4; ++j)
                acc[i][j] = MFMA16(af[i], bfr[j], acc[i][j]);
    }
    // ---- cross-half reduction through LDS (reuses As/Bs region) ----
    __syncthreads();               // all As/Bs reads complete block-wide
    float* red = (float*)smem;     // 256 threads x 32 floats = 32KB
    if (half == 1) {
#pragma unroll
        for (int i = 0; i < 2; ++i)
#pragma unroll
            for (int j = 0; j < 4; ++j) {
                int c = i * 4 + j;
                *(f32x4*)&red[htid * 32 + ((c ^ (htid & 7)) << 2)] = acc[i][j];
            }
    }
    __syncthreads();
    if (half == 0) {
#pragma unroll
        for (int i = 0; i < 2; ++i)
#pragma unroll
            for (int j = 0; j < 4; ++j) {
                int c = i * 4 + j;
                f32x4 o = *(const f32x4*)&red[htid * 32 + ((c ^ (htid & 7)) << 2)];
                acc[i][j] += o;
            }
#pragma unroll
        for (int j = 0; j < 4; ++j) {
            int col = bn + wn + j * 16 + lid;
            float bb = bias[col];
#pragma unroll
            for (int i = 0; i < 2; ++i) {
#pragma unroll
                for (int r = 0; r < 4; ++r) {
                    int row = bm + wm + i * 16 + quad * 4 + r;
                    float v = acc[i][j][r] + bb;
                    if (EPI == 2) {
                        ((float*)outp)[(size_t)row * N + col] = res[(size_t)row * N + col] + v;
                    } else {
                        ((bf16*)outp)[(size_t)row * N + col] = f2b(fmaxf(v, 0.f));
                    }
                }
            }
        }
    }
}

// ---------------- 64x96 GEMM (Wo projection), balanced grid + swizzle -------
template <int EPI>
__global__ __launch_bounds__(256) void gemm_ep96(const bf16* __restrict__ A,
                                                 const bf16* __restrict__ BT,
                                                 const float* __restrict__ bias,
                                                 const float* __restrict__ res,
                                                 void* __restrict__ outp,
                                                 int N, int K) {
    __shared__ bf16 As[2 * 64 * 32];    // 8 KB
    __shared__ bf16 Bs[2 * 96 * 32];    // 12 KB
    int wg = xcd_swz(blockIdx.x, gridDim.x);
    int bm = (wg / 8) * 64, bn = (wg % 8) * 96;
    int tid = threadIdx.x, wid = tid >> 6, lane = tid & 63, quad = lane >> 4, lid = lane & 15;
    int wm = (wid >> 1) * 32, wn = (wid & 1) * 48;
    f32x4 acc[2][3] = {};
    int ra = tid >> 2, ca = (tid & 3) ^ ((ra >> 1) & 3);
    int s0 = tid, s1 = tid + 256;            // B slots; s1 valid for tid<128 (rows 64..95)
    int rb0 = s0 >> 2, cb0 = (s0 & 3) ^ ((rb0 >> 1) & 3);
    int rb1 = s1 >> 2, cb1 = (s1 & 3) ^ ((rb1 >> 1) & 3);
    const bf16* Ap = A + (size_t)(bm + ra) * K + ca * 8;
    const bf16* B0 = BT + (size_t)(bn + rb0) * K + cb0 * 8;
    const bf16* B1 = BT + (size_t)(bn + rb1) * K + cb1 * 8;
    int rdc = quad ^ ((lid >> 1) & 3);
    bool doB1 = tid < 128;                   // wave-uniform (waves 0,1)
    g2l16(Ap, As + tid * 8);
    g2l16(B0, Bs + s0 * 8);
    if (doB1) g2l16(B1, Bs + s1 * 8);
    for (int k0 = 0; k0 < K; k0 += 32) {
        __syncthreads();
        int cur = (k0 >> 5) & 1;
        if (k0 + 32 < K) {
            g2l16(Ap + k0 + 32, As + (cur ^ 1) * 2048 + tid * 8);
            g2l16(B0 + k0 + 32, Bs + (cur ^ 1) * 3072 + s0 * 8);
            if (doB1) g2l16(B1 + k0 + 32, Bs + (cur ^ 1) * 3072 + s1 * 8);
        }
        const bf16* Ac = As + cur * 2048;
        const bf16* Bc = Bs + cur * 3072;
        bf16x8 af[2], bfr[3];
#pragma unroll
        for (int i = 0; i < 2; ++i) af[i]  = *(const bf16x8*)&Ac[(wm + i * 16 + lid) * 32 + rdc * 8];
#pragma unroll
        for (int j = 0; j < 3; ++j) bfr[j] = *(const bf16x8*)&Bc[(wn + j * 16 + lid) * 32 + rdc * 8];
#pragma unroll
        for (int i = 0; i < 2; ++i)
#pragma unroll
            for (int j = 0; j < 3; ++j)
                acc[i][j] = MFMA16(af[i], bfr[j], acc[i][j]);
    }
#pragma unroll
    for (int j = 0; j < 3; ++j) {
        int col = bn + wn + j * 16 + lid;
        float bb = bias[col];
#pragma unroll
        for (int i = 0; i < 2; ++i) {
#pragma unroll
            for (int r = 0; r < 4; ++r) {
                int row = bm + wm + i * 16 + quad * 4 + r;
                float v = acc[i][j][r] + bb;
                if (EPI == 2) {
                    ((float*)outp)[(size_t)row * N + col] = res[(size_t)row * N + col] + v;
                } else {
                    ((bf16*)outp)[(size_t)row * N + col] = f2b(fmaxf(v, 0.f));
                }
            }
        }
    }
}

// ---------------- flash attention, k-chunk partials (KCH=2) -----------------
// R3: QB=128, two 16-row q-strips per wave (kf/vf/mask reused across strips).
// R6: block-uniform mask fast-path. R8: s_setprio(1) around the MFMA-dense
// pa/ones/PV region (T5; m191 attn +4-7% with phase diversity — here 3
// independent blocks/CU give the scheduler cross-block diversity).
// grid (SS/128, 24, KCH) = 768 blocks; LDS ~50KB -> 3 blocks/CU.
__global__ __launch_bounds__(256) void attn_part(const bf16* __restrict__ qb,
                                                 const bf16* __restrict__ kb,
                                                 const bf16* __restrict__ vtb,
                                                 const int* __restrict__ mask,
                                                 bf16* __restrict__ part,
                                                 float* __restrict__ lws) {
    __shared__ bf16 Ks[2 * 64 * 64];
    __shared__ bf16 VTs[2 * 64 * 64];
    __shared__ bf16 Ps[128 * 72];   // [q][k], stride 72 -> b128 reads benign
    int bh = blockIdx.y;
    int b = bh / NH;
    int q0 = blockIdx.x * 128;
    int kc = blockIdx.z;
    const bf16* Kp = kb  + (size_t)bh * SS * DK;
    const bf16* VT = vtb + (size_t)bh * DK * SS;
    int tid = threadIdx.x, wid = tid >> 6, lane = tid & 63, quad = lane >> 4, lid = lane & 15;

    int s0 = tid, s1 = tid + 256;
    int r0 = s0 >> 3, c0 = (s0 & 7) ^ (r0 & 7);
    int r1 = s1 >> 3, c1 = (s1 & 7) ^ (r1 & 7);

    const int* mrow = mask + b * SS;
    int tbeg = kc * (SS / 64 / KCH), tend = (kc + 1) * (SS / 64 / KCH);

    // block-uniform mask check over this block's k-range (1024 ints = 256xint4)
    int myfull;
    {
        const int4* m4 = (const int4*)(mrow + tbeg * 64);
        int4 mm = m4[tid];
        myfull = (mm.x != 0) & (mm.y != 0) & (mm.z != 0) & (mm.w != 0);
    }
    int blockfull = __syncthreads_and(myfull);

    // Q fragments for both strips; same lane mapping serves as B-operand for S^T
    bf16x8 qf0[2], qf1[2];
#pragma unroll
    for (int u = 0; u < 2; ++u) {
        const bf16* Qrow = qb + ((size_t)bh * SS + q0 + wid * 32 + u * 16 + lid) * DK;
        qf0[u] = *(const bf16x8*)&Qrow[quad * 8];
        qf1[u] = *(const bf16x8*)&Qrow[32 + quad * 8];
    }

    bf16x8 ones;
#pragma unroll
    for (int i = 0; i < 8; ++i) ones[i] = (short)0x3F80;   // bf16 1.0

    int rdc  = quad ^ (lid & 7);
    int rdc2 = rdc ^ 4;

    f32x4 accv[2][4] = {};
    f32x4 accl[2] = {};

    // prologue: stage tile tbeg into buffer 0
    {
        int k0 = tbeg * 64;
        g2l16(Kp + (size_t)(k0 + r0) * DK + c0 * 8, Ks + s0 * 8);
        g2l16(Kp + (size_t)(k0 + r1) * DK + c1 * 8, Ks + s1 * 8);
        g2l16(VT + (size_t)r0 * SS + k0 + c0 * 8, VTs + s0 * 8);
        g2l16(VT + (size_t)r1 * SS + k0 + c1 * 8, VTs + s1 * 8);
    }

    int cur = 0;
    for (int t = tbeg; t < tend; ++t) {
        int k0 = t * 64;
        __syncthreads();   // buf[cur] staged (vmcnt drained); prev tile's reads done
        if (t + 1 < tend) {   // prefetch t+1 into alternate buffer
            int k0n = (t + 1) * 64;
            int nb = (cur ^ 1) * 4096;
            g2l16(Kp + (size_t)(k0n + r0) * DK + c0 * 8, Ks + nb + s0 * 8);
            g2l16(Kp + (size_t)(k0n + r1) * DK + c1 * 8, Ks + nb + s1 * 8);
            g2l16(VT + (size_t)r0 * SS + k0n + c0 * 8, VTs + nb + s0 * 8);
            g2l16(VT + (size_t)r1 * SS + k0n + c1 * 8, VTs + nb + s1 * 8);
        }
        const bf16* Kc  = Ks  + cur * 4096;
        const bf16* VTc = VTs + cur * 4096;

        // S^T: lane holds k = ns*16 + quad*4 + r, q = (strip base) + lid.
#pragma unroll
        for (int ns = 0; ns < 4; ++ns) {
            bf16x8 kf0 = *(const bf16x8*)&Kc[(ns * 16 + lid) * 64 + rdc * 8];
            bf16x8 kf1 = *(const bf16x8*)&Kc[(ns * 16 + lid) * 64 + rdc2 * 8];
#pragma unroll
            for (int u = 0; u < 2; ++u) {
                f32x4 st = {};
                st = MFMA16(kf0, qf0[u], st);
                st = MFMA16(kf1, qf1[u], st);
                float p0, p1, p2, p3;
                if (blockfull) {
                    p0 = EXP2F(st[0]);
                    p1 = EXP2F(st[1]);
                    p2 = EXP2F(st[2]);
                    p3 = EXP2F(st[3]);
                } else {
                    int4 mk = *(const int4*)&mrow[k0 + ns * 16 + quad * 4];
                    p0 = mk.x ? EXP2F(st[0]) : 0.f;
                    p1 = mk.y ? EXP2F(st[1]) : 0.f;
                    p2 = mk.z ? EXP2F(st[2]) : 0.f;
                    p3 = mk.w ? EXP2F(st[3]) : 0.f;
                }
                __hip_bfloat162 h01 = __float22bfloat162_rn(make_float2(p0, p1));
                __hip_bfloat162 h23 = __float22bfloat162_rn(make_float2(p2, p3));
                uint2 pw;
                pw.x = *(unsigned int*)&h01;
                pw.y = *(unsigned int*)&h23;
                *(uint2*)&Ps[(wid * 32 + u * 16 + lid) * 72 + ns * 16 + quad * 4] = pw;
            }
        }

        // P A-frags (same-wave round trip, no barrier); MFMA-dense region
        __builtin_amdgcn_s_setprio(1);
        bf16x8 pa0[2], pa1[2];
#pragma unroll
        for (int u = 0; u < 2; ++u) {
            pa0[u] = *(const bf16x8*)&Ps[(wid * 32 + u * 16 + lid) * 72 + quad * 8];
            pa1[u] = *(const bf16x8*)&Ps[(wid * 32 + u * 16 + lid) * 72 + 32 + quad * 8];
            accl[u] = MFMA16(pa0[u], ones, accl[u]);
            accl[u] = MFMA16(pa1[u], ones, accl[u]);
        }

        // PV: vf fragments loaded once, reused for both strips
#pragma unroll
        for (int ds = 0; ds < 4; ++ds) {
            bf16x8 vf0 = *(const bf16x8*)&VTc[(ds * 16 + lid) * 64 + rdc * 8];
            bf16x8 vf1 = *(const bf16x8*)&VTc[(ds * 16 + lid) * 64 + rdc2 * 8];
#pragma unroll
            for (int u = 0; u < 2; ++u) {
                accv[u][ds] = MFMA16(pa0[u], vf0, accv[u][ds]);
                accv[u][ds] = MFMA16(pa1[u], vf1, accv[u][ds]);
            }
        }
        __builtin_amdgcn_s_setprio(0);
        cur ^= 1;
    }

    bf16* pb = part + ((size_t)kc * (2 * NH) + bh) * DK * SS;
#pragma unroll
    for (int u = 0; u < 2; ++u) {
        if (lid == 0) {
#pragma unroll
            for (int r = 0; r < 4; ++r)
                lws[((size_t)kc * (2 * NH) + bh) * SS + q0 + wid * 32 + u * 16 + quad * 4 + r] = accl[u][r];
        }
        int qbase = q0 + wid * 32 + u * 16 + quad * 4;
#pragma unroll
        for (int ds = 0; ds < 4; ++ds) {
            int d = ds * 16 + lid;
            ushort4 pk;
            pk.x = f2b_bits(accv[u][ds][0]);
            pk.y = f2b_bits(accv[u][ds][1]);
            pk.z = f2b_bits(accv[u][ds][2]);
            pk.w = f2b_bits(accv[u][ds][3]);
            *(ushort4*)&pb[(size_t)d * SS + qbase] = pk;
        }
    }
}

// combine with LDS transpose: block per (64-q tile, bh).
__global__ __launch_bounds__(256) void attn_combine(const bf16* __restrict__ part,
                                                    const float* __restrict__ lws,
                                                    bf16* __restrict__ ctx) {
    __shared__ float tile[64][66];
    __shared__ float linv[64];
    int bh = blockIdx.y;
    int b = bh / NH, h = bh % NH;
    int q0 = blockIdx.x * 64;
    int tid = threadIdx.x;

    if (tid < 64) {
        float l = 0.f;
#pragma unroll
        for (int kc = 0; kc < KCH; ++kc)
            l += lws[((size_t)kc * (2 * NH) + bh) * SS + q0 + tid];
        linv[tid] = 1.f / l;
    }

    int d = tid >> 2, qs = (tid & 3) * 16;
    const bf16* p0 = part + (((size_t)0 * (2 * NH) + bh) * DK + d) * SS + q0 + qs;
    const bf16* p1 = part + (((size_t)1 * (2 * NH) + bh) * DK + d) * SS + q0 + qs;
    bf16x8 a0 = *(const bf16x8*)p0;
    bf16x8 a1 = *(const bf16x8*)(p0 + 8);
    bf16x8 b0 = *(const bf16x8*)p1;
    bf16x8 b1 = *(const bf16x8*)(p1 + 8);
#pragma unroll
    for (int i = 0; i < 8; ++i) {
        tile[d][qs + i]     = b2f(((const bf16*)&a0)[i]) + b2f(((const bf16*)&b0)[i]);
        tile[d][qs + 8 + i] = b2f(((const bf16*)&a1)[i]) + b2f(((const bf16*)&b1)[i]);
    }
    __syncthreads();

    int q = tid >> 2, ds2 = (tid & 3) * 16;
    float rl = linv[q];
    unsigned int wv[8];
#pragma unroll
    for (int i = 0; i < 8; ++i) {
        __hip_bfloat162 hh = __float22bfloat162_rn(
            make_float2(tile[ds2 + 2 * i][q] * rl, tile[ds2 + 2 * i + 1][q] * rl));
        wv[i] = *(unsigned int*)&hh;
    }
    bf16* crow = ctx + (size_t)(b * SS + q0 + q) * DM + h * DK + ds2;
    uint4 u0 = {wv[0], wv[1], wv[2], wv[3]};
    uint4 u1 = {wv[4], wv[5], wv[6], wv[7]};
    *(uint4*)&crow[0] = u0;
    *(uint4*)&crow[8] = u1;
}

// ---------------- host launch ----------------------------------------------
extern "C" void kernel_launch(void* const* d_in, const int* in_sizes, int n_in,
                              void* d_out, int out_size, void* d_ws, size_t ws_size,
                              hipStream_t stream) {
    const float* x    = (const float*)d_in[0];
    const int*   mask = (const int*)d_in[1];
    const float* Wq   = (const float*)d_in[2];
    const float* bq   = (const float*)d_in[3];
    const float* Wk   = (const float*)d_in[4];
    const float* bk   = (const float*)d_in[5];
    const float* Wv   = (const float*)d_in[6];
    const float* bv   = (const float*)d_in[7];
    const float* Wo   = (const float*)d_in[8];
    const float* bo   = (const float*)d_in[9];
    const float* ln1a = (const float*)d_in[10];
    const float* ln1b = (const float*)d_in[11];
    const float* W1   = (const float*)d_in[12];
    const float* b1   = (const float*)d_in[13];
    const float* W2   = (const float*)d_in[14];
    const float* b2   = (const float*)d_in[15];
    const float* ln2a = (const float*)d_in[16];
    const float* ln2b = (const float*)d_in[17];
    float* out = (float*)d_out;

    char* w = (char*)d_ws;
    bf16* h   = (bf16*)w; w += (size_t)NTOK * DM * 2;
    bf16* qb  = (bf16*)w; w += (size_t)NTOK * DM * 2;
    bf16* kb  = (bf16*)w; w += (size_t)NTOK * DM * 2;
    bf16* vtb = (bf16*)w; w += (size_t)NTOK * DM * 2;
    bf16* ctx = (bf16*)w; w += (size_t)NTOK * DM * 2;
    bf16* h2  = (bf16*)w; w += (size_t)NTOK * DM * 2;
    bf16* ffa = (bf16*)w; w += (size_t)NTOK * DFF * 2;   // also attn partials (temporally disjoint)
    float* x1 = (float*)w; w += (size_t)NTOK * DM * 4;   // also attn l-partials (temporally disjoint)
    bf16* WqT = (bf16*)w; w += (size_t)DM * DM * 2;
    bf16* WkT = (bf16*)w; w += (size_t)DM * DM * 2;
    bf16* WvT = (bf16*)w; w += (size_t)DM * DM * 2;
    bf16* WoT = (bf16*)w; w += (size_t)DM * DM * 2;
    bf16* W1T = (bf16*)w; w += (size_t)DM * DFF * 2;
    bf16* W2T = (bf16*)w; w += (size_t)DM * DFF * 2;

    bf16*  part = ffa;          // KCH*2*NH*DK*SS*2 = 12.6 MB <= NTOK*DFF*2 (24 MB)
    float* lws  = x1;           // KCH*24*SS*4 = 384 KB < NTOK*DM*4

    fused_pre<<<6912 + NTOK / 4, 256, 0, stream>>>(Wq, Wk, Wv, Wo, W1, W2,
                                                   WqT, WkT, WvT, WoT, W1T, W2T,
                                                   x, ln1a, ln1b, h);
    gemm_qkv<<<768, 256, 0, stream>>>(h, WqT, WkT, WvT, bq, bk, bv, qb, kb, vtb);
    attn_part<<<dim3(SS / 128, 2 * NH, KCH), 256, 0, stream>>>(qb, kb, vtb, mask, part, lws);
    attn_combine<<<dim3(SS / 64, 2 * NH), 256, 0, stream>>>(part, lws, ctx);
    gemm_ep96<2><<<512, 256, 0, stream>>>(ctx, WoT, bo, x, (void*)x1, DM, DM);
    ln_fwd<<<NTOK / 4, 256, 0, stream>>>(x1, ln2a, ln2b, h2);
    gemm_ep<3><<<768, 256, 0, stream>>>(h2, W1T, b1, nullptr, (void*)ffa, DFF, DM);
    gemm_ep64<2><<<384, 512, 0, stream>>>(ffa, W2T, b2, x1, (void*)out, DM, DFF);
}